// Round 15
// baseline (692.273 us; speedup 1.0000x reference)
//
#include <hip/hip_runtime.h>
#include <hip/hip_bf16.h>

// DGCNN-style KNN classifier. B=8, N=2048, K=10.
// g_flag=1 -> bf16 inputs, 0 -> fp32 (runtime probe). Output same dtype.
// Scratch in static __device__ globals; every byte read is written earlier in
// the same launch (graph-replay safe; norms for layer-3 epi are re-zeroed
// each launch before the atomicAdd pass).
//
// R14->R15: (1) NPART 4->8 (2048 blocks = 8/CU; knn was ~50% stall-bound at
// 4 waves/SIMD) + LDS squeezed to exactly 20480B (th overlaid in spool tail)
// so 8 blocks/CU fit. (2) norms + knn-split + W5-split fused into the edge
// epilogue (value is in-register there); fp32 cat is dead; removes 8
// dispatches and a full read pass. Numerics identical.

#define NEG 0.2f
#define FMAX 3.402823466e+38f
#define KINIT 0x7F7FFFFFFFFFFFFFull  // (FLT_MAX bits << 32) | 0xFFFFFFFF

typedef __hip_bfloat16 bf16;
typedef __attribute__((ext_vector_type(8))) short s8v;    // 8 bf16
typedef __attribute__((ext_vector_type(4))) float f32x4;  // MFMA acc
typedef unsigned long long u64;

#define BB 8
#define NN 2048
#define BNTOT (BB * NN)
#define NPART 8

#define OFF_NORMS ((size_t)0)
#define OFF_PART (OFF_NORMS + BNTOT)
#define OFF_POOLED (OFF_PART + 8 * 1024 * 32)
#define OFF_H1 (OFF_POOLED + 8 * 1024)
#define OFF_H2 (OFF_H1 + 8 * 512)
#define WSF_TOTAL (OFF_H2 + 8 * 256)

__device__ float g_ws_f[WSF_TOTAL];
__device__ float g_G[(size_t)8 * BNTOT * 64];     // [chunk(<=4)][z(2)][BN][64]
__device__ int g_ws_i[(size_t)BNTOT * 10];        // final knn idx
__device__ u64 g_pk[(size_t)BNTOT * NPART * 10];  // partial top-10 packed keys
__device__ int g_flag;                            // 1 = bf16 inputs, 0 = fp32
__device__ unsigned short g_hi[(size_t)BNTOT * 512];    // knn/gmat split (frag-tiled)
__device__ unsigned short g_lo[(size_t)BNTOT * 512];
__device__ unsigned short g_xhi5[(size_t)BNTOT * 512];  // W5-layout activations
__device__ unsigned short g_xlo5[(size_t)BNTOT * 512];
__device__ unsigned short g_whi[1024 * 512];            // split W5 weights
__device__ unsigned short g_wlo[1024 * 512];

__device__ __forceinline__ float ldany(const void* p, size_t i, int isb) {
  if (isb) return __bfloat162float(((const bf16*)p)[i]);
  return ((const float*)p)[i];
}

// ---------------- dtype probe ----------------
__global__ void probe_kernel(const void* pts) {
  const unsigned* w = (const unsigned*)pts;
  int cnt = 0;
  for (int i = 0; i < 256; ++i) {
    unsigned e2 = (w[i] >> 7) & 0xFF;
    cnt += (e2 >= 110 && e2 <= 135);
  }
  g_flag = (cnt > 128) ? 1 : 0;
}

// ---------------- norms (layer-1 input only) ----------------
__global__ void norms_kernel(const void* xraw, int lda, int C, int BN) {
  const int isb = g_flag;
  float* norms = g_ws_f + OFF_NORMS;
  int row = blockIdx.x * (blockDim.x >> 6) + (threadIdx.x >> 6);
  int lane = threadIdx.x & 63;
  if (row >= BN) return;
  float s = 0.f;
  for (int c = lane; c < C; c += 64) {
    float v = ldany(xraw, (size_t)row * lda + c, isb);
    s += v * v;
  }
#pragma unroll
  for (int off = 32; off > 0; off >>= 1) s += __shfl_down(s, off, 64);
  if (lane == 0) norms[row] = s;
}

__global__ void zero_norms() {
  int i = blockIdx.x * blockDim.x + threadIdx.x;
  if (i < BNTOT) g_ws_f[OFF_NORMS + i] = 0.f;
}

// ------- split-bf16 into MFMA-fragment-tile layout (points + W5 weights) -------
__global__ void split_kernel(const void* xraw, int lda, int C,
                             int csh2, int dst, int total) {
  int i = blockIdx.x * blockDim.x + threadIdx.x;
  if (i >= total) return;
  const int isb = g_flag;
  int t = i >> 9, win = i & 511;
  int quad = win >> 7, l16 = (win >> 3) & 15, j = win & 7;
  int ktiles_m1 = (1 << csh2) - 1;
  int rg = t >> csh2, kt = t & ktiles_m1;
  int r = rg * 16 + l16;
  int c = kt * 32 + quad * 8 + j;
  float v = (c < C) ? ldany(xraw, (size_t)r * lda + c, isb) : 0.f;
  bf16 h = __float2bfloat16(v);
  float hf = __bfloat162float(h);
  bf16 l = __float2bfloat16(v - hf);
  unsigned short* H = dst ? g_whi : g_hi;
  unsigned short* L = dst ? g_wlo : g_lo;
  H[i] = *(unsigned short*)&h;
  L[i] = *(unsigned short*)&l;
}

// ------- fused KNN (partitioned): MFMA distances + per-partition top-10 -------
template <int CPAD>
__global__ __launch_bounds__(256) void knn_fused(int N) {
  constexpr int KT = CPAD >> 5;
  __shared__ u64 spool[2560];  // 20480 B: sd[64][68] (17408B) + th overlay + merge
  float* sd = (float*)spool;
  float* th = (float*)(spool + 2176);  // 256 floats right after sd
  const int tid = threadIdx.x;
  const int wave = tid >> 6, lane = tid & 63;
  const int quad = lane >> 4, l16 = lane & 15;
  const int b = blockIdx.y;
  const int q0 = blockIdx.x * 64;
  const int part = blockIdx.z;
  const int PN = N / NPART;
  const size_t rowb = (size_t)b * N;
  const float* norms = g_ws_f + OFF_NORMS;

  const int arg = (int)((rowb + q0) >> 4) + wave;
  s8v ah[KT], al[KT];
#pragma unroll
  for (int kt = 0; kt < KT; ++kt) {
    const size_t abase = ((size_t)arg * KT + kt) * 512 + lane * 8;
    ah[kt] = *(const s8v*)(g_hi + abase);
    al[kt] = *(const s8v*)(g_lo + abase);
  }

  const int selfn = q0 + lane;  // this thread maintains query q0+lane
  const float qn = norms[rowb + selfn];
  u64 K[10];
#pragma unroll
  for (int i = 0; i < 10; ++i) K[i] = KINIT;
  th[wave * 64 + lane] = FMAX;  // covered by first in-loop barrier

  for (int m0 = part * PN; m0 < (part + 1) * PN; m0 += 64) {
    f32x4 acc[4];
#pragma unroll
    for (int s = 0; s < 4; ++s) acc[s] = (f32x4){0.f, 0.f, 0.f, 0.f};
    const int brg0 = (int)((rowb + m0) >> 4);
#pragma unroll
    for (int kt = 0; kt < KT; ++kt) {
#pragma unroll
      for (int s = 0; s < 4; ++s) {
        const size_t bbase = ((size_t)(brg0 + s) * KT + kt) * 512 + lane * 8;
        s8v bh = *(const s8v*)(g_hi + bbase);
        s8v bl = *(const s8v*)(g_lo + bbase);
        acc[s] = __builtin_amdgcn_mfma_f32_16x16x32_bf16(ah[kt], bh, acc[s], 0, 0, 0);
        acc[s] = __builtin_amdgcn_mfma_f32_16x16x32_bf16(ah[kt], bl, acc[s], 0, 0, 0);
        acc[s] = __builtin_amdgcn_mfma_f32_16x16x32_bf16(al[kt], bh, acc[s], 0, 0, 0);
      }
    }
    __syncthreads();  // previous tile's scan done before overwrite
#pragma unroll
    for (int s = 0; s < 4; ++s) {
      int ml = s * 16 + l16;
      float nm = norms[rowb + m0 + ml];
#pragma unroll
      for (int r = 0; r < 4; ++r)
        sd[(wave * 16 + quad * 4 + r) * 68 + ml] = nm - 2.f * acc[s][r];
    }
    __syncthreads();
    // shared threshold: min over 4 waves of this query's K[9] dist (any value
    // ever in th >= final 10th-best, so races only loosen safely)
    const float T = fminf(fminf(th[lane], th[64 + lane]),
                          fminf(th[128 + lane], th[192 + lane]));
    // phase 1: filter d_raw + qn <= T (exclusion-safe; exact u64 in phase 2)
    const int mbase = m0 + wave * 16;
    const float* srow = sd + lane * 68 + wave * 16;
    unsigned pass = 0;
#pragma unroll
    for (int jj = 0; jj < 16; jj += 4) {
      float4 d4 = *(const float4*)(srow + jj);
      pass |= (unsigned)(d4.x + qn <= T) << jj;
      pass |= (unsigned)(d4.y + qn <= T) << (jj + 1);
      pass |= (unsigned)(d4.z + qn <= T) << (jj + 2);
      pass |= (unsigned)(d4.w + qn <= T) << (jj + 3);
    }
    if ((unsigned)(selfn - mbase) < 16u) pass &= ~(1u << (selfn - mbase));
    // phase 2: insert only passing candidates (exact keys)
    while (pass) {
      int jj = __builtin_ctz(pass);
      pass &= pass - 1;
      int m = mbase + jj;
      float d = fmaxf(srow[jj] + qn, 0.f);
      u64 key = ((u64)__float_as_uint(d) << 32) | (unsigned)m;
      if (key < K[9]) {
        bool prev = true;
#pragma unroll
        for (int s2 = 9; s2 >= 1; --s2) {
          bool sh = key < K[s2 - 1];
          K[s2] = sh ? K[s2 - 1] : (prev ? key : K[s2]);
          prev = sh;
        }
        if (prev) K[0] = key;
      }
    }
    th[wave * 64 + lane] = __uint_as_float((unsigned)(K[9] >> 32));
  }
  __syncthreads();  // sd/th dead; reuse spool for merge lists
#pragma unroll
  for (int i = 0; i < 10; ++i) spool[(lane * 4 + wave) * 10 + i] = K[i];
  __syncthreads();
  if (tid < 64) {
    int q = tid;
    int p0 = 0, p1 = 0, p2 = 0, p3 = 0;
    size_t ob = ((rowb + q0 + q) * NPART + part) * 10;
    for (int cnt = 0; cnt < 10; ++cnt) {
      u64 k0 = spool[(q * 4 + 0) * 10 + p0];
      u64 k1 = spool[(q * 4 + 1) * 10 + p1];
      u64 k2 = spool[(q * 4 + 2) * 10 + p2];
      u64 k3 = spool[(q * 4 + 3) * 10 + p3];
      u64 bk = k0; int bp = 0;
      if (k1 < bk) { bk = k1; bp = 1; }
      if (k2 < bk) { bk = k2; bp = 2; }
      if (k3 < bk) { bk = k3; bp = 3; }
      if (bp == 0) ++p0; else if (bp == 1) ++p1; else if (bp == 2) ++p2; else ++p3;
      g_pk[ob + cnt] = bk;
    }
  }
}

// ------- merge NPART sorted partial lists per query -> final top-10 -------
__global__ void knn_merge() {
  int row = blockIdx.x * blockDim.x + threadIdx.x;
  if (row >= BNTOT) return;
  const u64* pk = g_pk + (size_t)row * NPART * 10;
  int ptr[NPART];
#pragma unroll
  for (int p = 0; p < NPART; ++p) ptr[p] = 0;
  int* ob = g_ws_i + (size_t)row * 10;
  for (int k = 0; k < 10; ++k) {
    u64 bk = ~0ULL; int bp = 0;
#pragma unroll
    for (int p = 0; p < NPART; ++p) {
      u64 key = pk[p * 10 + ptr[p]];
      if (key < bk) { bk = key; bp = p; }
    }
#pragma unroll
    for (int p = 0; p < NPART; ++p) ptr[p] += (p == bp);
    ob[k] = (int)(bk & 0xFFFFFFFFu);
  }
}

// --- G[chunk][z] = X @ W_half^T via MFMA; A from frag-tiled g_hi/g_lo ---
template <int CPAD>
__global__ __launch_bounds__(256) void gmat_mfma(const void* W, int C, int BN) {
  constexpr int KT = CPAD >> 5;
  __shared__ __align__(16) unsigned short wbh[4 * KT * 512];
  __shared__ __align__(16) unsigned short wbl[4 * KT * 512];
  const int isb = g_flag;
  const int tid = threadIdx.x;
  const int wave = tid >> 6, lane = tid & 63;
  const int quad = lane >> 4, l16 = lane & 15;
  const int r0 = blockIdx.x * 64;
  const int chunk = blockIdx.y;
  const int z = blockIdx.z;
  const int o_base = chunk * 64;
  for (int i = tid; i < 4 * KT * 512; i += 256) {
    int t = i >> 9, win = i & 511;
    int q2 = win >> 7, s16 = (win >> 3) & 15, j = win & 7;
    int s = t / KT, kt = t % KT;
    int orow = o_base + s * 16 + s16;
    int c = kt * 32 + q2 * 8 + j;
    float v = (c < C) ? ldany(W, (size_t)orow * (2 * C) + (size_t)z * C + c, isb) : 0.f;
    bf16 h = __float2bfloat16(v);
    float hf = __bfloat162float(h);
    bf16 l = __float2bfloat16(v - hf);
    wbh[i] = *(unsigned short*)&h;
    wbl[i] = *(unsigned short*)&l;
  }
  __syncthreads();
  f32x4 acc[4];
#pragma unroll
  for (int s = 0; s < 4; ++s) acc[s] = (f32x4){0.f, 0.f, 0.f, 0.f};
  const int arg = (r0 >> 4) + wave;
#pragma unroll
  for (int kt = 0; kt < KT; ++kt) {
    const size_t abase = ((size_t)arg * KT + kt) * 512 + lane * 8;
    s8v ah = *(const s8v*)(g_hi + abase);
    s8v al = *(const s8v*)(g_lo + abase);
#pragma unroll
    for (int s = 0; s < 4; ++s) {
      const int woff = (s * KT + kt) * 512 + lane * 8;
      s8v bh = *(const s8v*)(wbh + woff);
      s8v bl = *(const s8v*)(wbl + woff);
      acc[s] = __builtin_amdgcn_mfma_f32_16x16x32_bf16(ah, bh, acc[s], 0, 0, 0);
      acc[s] = __builtin_amdgcn_mfma_f32_16x16x32_bf16(ah, bl, acc[s], 0, 0, 0);
      acc[s] = __builtin_amdgcn_mfma_f32_16x16x32_bf16(al, bh, acc[s], 0, 0, 0);
    }
  }
  float* Gz = g_G + (size_t)(chunk * 2 + z) * BN * 64;
#pragma unroll
  for (int s = 0; s < 4; ++s)
#pragma unroll
    for (int r = 0; r < 4; ++r)
      Gz[(size_t)(r0 + wave * 16 + quad * 4 + r) * 64 + s * 16 + l16] = acc[s][r];
}

// ------- edge-conv epilogue: gather+max, then fused splits + norms -------
// writes: knn-layout g_hi/g_lo (if knn_csh2>=0), W5-layout g_xhi5/g_xlo5,
// norms (mode 1 = store, 2 = atomicAdd; caller zeroes first for mode 2).
__global__ void edge_epi64(const void* s, const void* t, int colbase,
                           int knn_csh2, int norms_mode, int BN, int N) {
  const int isb = g_flag;
  int tid = threadIdx.x;
  int p = tid >> 6, o = tid & 63;
  int row = blockIdx.x * 4 + p;
  int chunk = blockIdx.y;
  const float* G1 = g_G + (size_t)(chunk * 2 + 0) * BN * 64;
  const float* G2 = g_G + (size_t)(chunk * 2 + 1) * BN * 64;
  int b = row / N;
  const int* id = g_ws_i + (size_t)row * 10;
  float g1n = G1[(size_t)row * 64 + o];
  float base = G2[(size_t)row * 64 + o] - g1n;
  int co = chunk * 64 + o;  // channel within this layer's output slice
  float sv = ldany(s, co, isb), tv = ldany(t, co, isb);
  float mx = -FMAX;
#pragma unroll
  for (int k = 0; k < 10; ++k) {
    int m = id[k];
    m = (m < 0) ? 0 : ((m >= N) ? N - 1 : m);
    float h = sv * (G1[((size_t)b * N + m) * 64 + o] + base) + tv;
    h = (h >= 0.f) ? h : NEG * h;
    mx = fmaxf(mx, h);
  }
  // split mx -> hi/lo bf16
  bf16 h16 = __float2bfloat16(mx);
  float hf = __bfloat162float(h16);
  bf16 l16v = __float2bfloat16(mx - hf);
  unsigned short hu = *(unsigned short*)&h16;
  unsigned short lu = *(unsigned short*)&l16v;
  // knn-layout write (next layer's input slice, CPAD = 32<<knn_csh2)
  if (knn_csh2 >= 0) {
    int KTL = 1 << knn_csh2;
    size_t ki = ((size_t)(row >> 4) * KTL + (co >> 5)) * 512 +
                ((size_t)((co >> 3) & 3)) * 128 + (row & 15) * 8 + (co & 7);
    g_hi[ki] = hu; g_lo[ki] = lu;
  }
  // W5-layout write (global col = colbase + co, CPAD 512, KT=16)
  {
    int gc = colbase + co;
    size_t wi = ((size_t)(row >> 4) * 16 + (gc >> 5)) * 512 +
                ((size_t)((gc >> 3) & 3)) * 128 + (row & 15) * 8 + (gc & 7);
    g_xhi5[wi] = hu; g_xlo5[wi] = lu;
  }
  // norms: wave-reduce sum(mx^2) over this row's 64 channels in this chunk
  if (norms_mode) {
    float ns = mx * mx;
#pragma unroll
    for (int off = 32; off > 0; off >>= 1) ns += __shfl_down(ns, off, 64);
    if (o == 0) {
      if (norms_mode == 1) g_ws_f[OFF_NORMS + row] = ns;
      else atomicAdd(&g_ws_f[OFF_NORMS + row], ns);
    }
  }
}

// ------- W5 MFMA + max over n; wave tile 32n x 64o (s5>0: affine after max) ----
__global__ __launch_bounds__(256) void w5max_mfma(const void* s5, const void* t5, int N) {
  const int tid = threadIdx.x;
  const int wave = tid >> 6, lane = tid & 63;
  const int quad = lane >> 4, l16 = lane & 15;
  const int b = blockIdx.z;
  const int o0 = blockIdx.y * 64, n0 = blockIdx.x * 128;
  f32x4 acc[2][4];
#pragma unroll
  for (int a = 0; a < 2; ++a)
#pragma unroll
    for (int s = 0; s < 4; ++s) acc[a][s] = (f32x4){0.f, 0.f, 0.f, 0.f};

  const int arg0 = (int)(((size_t)b * N + n0) >> 4) + wave * 2;
  const int wrg0 = o0 >> 4;
#pragma unroll 2
  for (int kt = 0; kt < 16; ++kt) {
    s8v ah[2], al[2];
#pragma unroll
    for (int a = 0; a < 2; ++a) {
      const size_t abase = ((size_t)(arg0 + a) * 16 + kt) * 512 + lane * 8;
      ah[a] = *(const s8v*)(g_xhi5 + abase);
      al[a] = *(const s8v*)(g_xlo5 + abase);
    }
#pragma unroll
    for (int s = 0; s < 4; ++s) {
      const size_t bbase = ((size_t)(wrg0 + s) * 16 + kt) * 512 + lane * 8;
      s8v bh = *(const s8v*)(g_whi + bbase);
      s8v bl = *(const s8v*)(g_wlo + bbase);
#pragma unroll
      for (int a = 0; a < 2; ++a) {
        acc[a][s] = __builtin_amdgcn_mfma_f32_16x16x32_bf16(ah[a], bh, acc[a][s], 0, 0, 0);
        acc[a][s] = __builtin_amdgcn_mfma_f32_16x16x32_bf16(ah[a], bl, acc[a][s], 0, 0, 0);
        acc[a][s] = __builtin_amdgcn_mfma_f32_16x16x32_bf16(al[a], bh, acc[a][s], 0, 0, 0);
      }
    }
  }
  __shared__ float red[4][64];
  const int isb = g_flag;
#pragma unroll
  for (int s = 0; s < 4; ++s) {
    float m4 = -FMAX;
#pragma unroll
    for (int a = 0; a < 2; ++a)
#pragma unroll
      for (int r = 0; r < 4; ++r) m4 = fmaxf(m4, acc[a][s][r]);
#pragma unroll
    for (int off = 16; off < 64; off <<= 1) m4 = fmaxf(m4, __shfl_down(m4, off, 64));
    if (quad == 0) red[wave][s * 16 + l16] = m4;
  }
  __syncthreads();
  if (tid < 64) {
    float m = fmaxf(fmaxf(red[0][tid], red[1][tid]), fmaxf(red[2][tid], red[3][tid]));
    int o = o0 + tid;
    float sv = ldany(s5, o, isb), tv = ldany(t5, o, isb);
    float h = sv * m + tv;
    h = (h >= 0.f) ? h : NEG * h;
    g_ws_f[OFF_PART + ((size_t)b * 1024 + o) * 16 + blockIdx.x] = h;
  }
}

__global__ void poolred_kernel() {
  const float* part = g_ws_f + OFF_PART;
  float* pooled = g_ws_f + OFF_POOLED;
  int i = blockIdx.x * blockDim.x + threadIdx.x;
  if (i >= 8 * 1024) return;
  const float* p = part + (size_t)i * 16;
  float m = -FMAX;
#pragma unroll
  for (int j = 0; j < 16; ++j) m = fmaxf(m, p[j]);
  pooled[i] = m;
}

// ---------------- FC: one wave per output ----------------
__global__ void fc_kernel(size_t inoff, const void* W, const void* bias,
                          const void* s, const void* t, size_t outoff, int has_out,
                          void* OUTB, int Bb, int IC, int OC, int act) {
  const int isb = g_flag;
  const float* IN = g_ws_f + inoff;
  int gw = (blockIdx.x * blockDim.x + threadIdx.x) >> 6;
  int lane = threadIdx.x & 63;
  if (gw >= Bb * OC) return;
  int b = gw / OC, o = gw % OC;
  const float* in = IN + (size_t)b * IC;
  float acc = 0.f;
  for (int c = lane; c < IC; c += 64) acc += in[c] * ldany(W, (size_t)o * IC + c, isb);
#pragma unroll
  for (int off = 32; off > 0; off >>= 1) acc += __shfl_down(acc, off, 64);
  if (lane == 0) {
    float h = acc;
    if (bias) h += ldany(bias, o, isb);
    if (s) h = h * ldany(s, o, isb) + ldany(t, o, isb);
    if (act) h = (h >= 0.f) ? h : NEG * h;
    if (has_out) g_ws_f[outoff + (size_t)b * OC + o] = h;
    if (OUTB) {
      if (isb) ((bf16*)OUTB)[(size_t)b * OC + o] = __float2bfloat16(h);
      else ((float*)OUTB)[(size_t)b * OC + o] = h;
    }
  }
}

extern "C" void kernel_launch(void* const* d_in, const int* in_sizes, int n_in,
                              void* d_out, int out_size, void* d_ws, size_t ws_size,
                              hipStream_t stream) {
  const int B = 8, N = 2048, BN = B * N;
  const void* points = d_in[0];
  const void *W1 = d_in[1], *s1 = d_in[2], *t1 = d_in[3];
  const void *W2 = d_in[4], *s2 = d_in[5], *t2 = d_in[6];
  const void *W3 = d_in[7], *s3 = d_in[8], *t3 = d_in[9];
  const void *W4 = d_in[10], *s4 = d_in[11], *t4 = d_in[12];
  const void *W5 = d_in[13], *s5 = d_in[14], *t5 = d_in[15];
  const void *Wf1 = d_in[16], *sf1 = d_in[17], *tf1 = d_in[18];
  const void *Wf2 = d_in[19], *bf2 = d_in[20], *sf2 = d_in[21], *tf2 = d_in[22];
  const void *Wf3 = d_in[23], *bf3 = d_in[24];

  probe_kernel<<<1, 1, 0, stream>>>(points);
  split_kernel<<<(1024 * 512) / 256, 256, 0, stream>>>(W5, 512, 512, 4, 1, 1024 * 512);

  // ---- layer 1: points (C=3, CPAD=32) -> cols 0:64
  norms_kernel<<<BN / 4, 256, 0, stream>>>(points, 3, 3, BN);
  split_kernel<<<(BN * 32) / 256, 256, 0, stream>>>(points, 3, 3, 0, 0, BN * 32);
  knn_fused<32><<<dim3(N / 64, B, NPART), 256, 0, stream>>>(N);
  knn_merge<<<BN / 256, 256, 0, stream>>>();
  gmat_mfma<32><<<dim3(BN / 64, 1, 2), 256, 0, stream>>>(W1, 3, BN);
  edge_epi64<<<dim3(BN / 4, 1), 256, 0, stream>>>(s1, t1, 0, 1, 1, BN, N);
  // ---- layer 2: (C=64, CPAD=64) -> cols 64:128
  knn_fused<64><<<dim3(N / 64, B, NPART), 256, 0, stream>>>(N);
  knn_merge<<<BN / 256, 256, 0, stream>>>();
  gmat_mfma<64><<<dim3(BN / 64, 1, 2), 256, 0, stream>>>(W2, 64, BN);
  edge_epi64<<<dim3(BN / 4, 1), 256, 0, stream>>>(s2, t2, 64, 1, 1, BN, N);
  // ---- layer 3: (C=64) -> cols 128:256, 2 chunks; next layer CPAD=128
  knn_fused<64><<<dim3(N / 64, B, NPART), 256, 0, stream>>>(N);
  knn_merge<<<BN / 256, 256, 0, stream>>>();
  gmat_mfma<64><<<dim3(BN / 64, 2, 2), 256, 0, stream>>>(W3, 64, BN);
  zero_norms<<<BN / 256, 256, 0, stream>>>();
  edge_epi64<<<dim3(BN / 4, 2), 256, 0, stream>>>(s3, t3, 128, 2, 2, BN, N);
  // ---- layer 4: (C=128) -> cols 256:512, 4 chunks; no next knn
  knn_fused<128><<<dim3(N / 64, B, NPART), 256, 0, stream>>>(N);
  knn_merge<<<BN / 256, 256, 0, stream>>>();
  gmat_mfma<128><<<dim3(BN / 64, 4, 2), 256, 0, stream>>>(W4, 128, BN);
  edge_epi64<<<dim3(BN / 4, 4), 256, 0, stream>>>(s4, t4, 256, -1, 0, BN, N);
  // ---- W5 + global max pool
  w5max_mfma<<<dim3(16, 16, 8), 256, 0, stream>>>(s5, t5, N);
  poolred_kernel<<<32, 256, 0, stream>>>();
  // ---- FC head
  fc_kernel<<<(8 * 512 * 64) / 256, 256, 0, stream>>>(OFF_POOLED, Wf1, nullptr, sf1, tf1, OFF_H1, 1, nullptr, 8, 1024, 512, 1);
  fc_kernel<<<(8 * 256 * 64) / 256, 256, 0, stream>>>(OFF_H1, Wf2, bf2, sf2, tf2, OFF_H2, 1, nullptr, 8, 512, 256, 1);
  fc_kernel<<<6, 256, 0, stream>>>(OFF_H2, Wf3, bf3, nullptr, nullptr, 0, 0, d_out, 8, 256, 3, 0);
}

// Round 16
// 612.986 us; speedup vs baseline: 1.1293x; 1.1293x over previous
//
#include <hip/hip_runtime.h>
#include <hip/hip_bf16.h>

// DGCNN-style KNN classifier. B=8, N=2048, K=10.
// g_flag=1 -> bf16 inputs, 0 -> fp32 (runtime probe). Output same dtype.
// Scratch in static __device__ globals; every byte read is written earlier in
// the same launch (graph-replay safe; layer-3 norms re-zeroed before atomics).
//
// R15->R16: NPART back to 4 (8 doubled list count + halved threshold
// convergence -> knn 88->102 regression). Kept fused epilogue. NEW:
// double-buffered sd -> ONE barrier per tile (write buf[t&1] can only
// collide with scans of t-2, finished before barrier t-1). LDS 35.8KB =
// 4 blocks/CU, matches 1024-block grid. Selection bit-identical.

#define NEG 0.2f
#define FMAX 3.402823466e+38f
#define KINIT 0x7F7FFFFFFFFFFFFFull  // (FLT_MAX bits << 32) | 0xFFFFFFFF

typedef __hip_bfloat16 bf16;
typedef __attribute__((ext_vector_type(8))) short s8v;    // 8 bf16
typedef __attribute__((ext_vector_type(4))) float f32x4;  // MFMA acc
typedef unsigned long long u64;

#define BB 8
#define NN 2048
#define BNTOT (BB * NN)
#define NPART 4

#define OFF_NORMS ((size_t)0)
#define OFF_PART (OFF_NORMS + BNTOT)
#define OFF_POOLED (OFF_PART + 8 * 1024 * 32)
#define OFF_H1 (OFF_POOLED + 8 * 1024)
#define OFF_H2 (OFF_H1 + 8 * 512)
#define WSF_TOTAL (OFF_H2 + 8 * 256)

__device__ float g_ws_f[WSF_TOTAL];
__device__ float g_G[(size_t)8 * BNTOT * 64];     // [chunk(<=4)][z(2)][BN][64]
__device__ int g_ws_i[(size_t)BNTOT * 10];        // final knn idx
__device__ u64 g_pk[(size_t)BNTOT * NPART * 10];  // partial top-10 packed keys
__device__ int g_flag;                            // 1 = bf16 inputs, 0 = fp32
__device__ unsigned short g_hi[(size_t)BNTOT * 512];    // knn/gmat split (frag-tiled)
__device__ unsigned short g_lo[(size_t)BNTOT * 512];
__device__ unsigned short g_xhi5[(size_t)BNTOT * 512];  // W5-layout activations
__device__ unsigned short g_xlo5[(size_t)BNTOT * 512];
__device__ unsigned short g_whi[1024 * 512];            // split W5 weights
__device__ unsigned short g_wlo[1024 * 512];

__device__ __forceinline__ float ldany(const void* p, size_t i, int isb) {
  if (isb) return __bfloat162float(((const bf16*)p)[i]);
  return ((const float*)p)[i];
}

// ---------------- dtype probe ----------------
__global__ void probe_kernel(const void* pts) {
  const unsigned* w = (const unsigned*)pts;
  int cnt = 0;
  for (int i = 0; i < 256; ++i) {
    unsigned e2 = (w[i] >> 7) & 0xFF;
    cnt += (e2 >= 110 && e2 <= 135);
  }
  g_flag = (cnt > 128) ? 1 : 0;
}

// ---------------- norms (layer-1 input only) ----------------
__global__ void norms_kernel(const void* xraw, int lda, int C, int BN) {
  const int isb = g_flag;
  float* norms = g_ws_f + OFF_NORMS;
  int row = blockIdx.x * (blockDim.x >> 6) + (threadIdx.x >> 6);
  int lane = threadIdx.x & 63;
  if (row >= BN) return;
  float s = 0.f;
  for (int c = lane; c < C; c += 64) {
    float v = ldany(xraw, (size_t)row * lda + c, isb);
    s += v * v;
  }
#pragma unroll
  for (int off = 32; off > 0; off >>= 1) s += __shfl_down(s, off, 64);
  if (lane == 0) norms[row] = s;
}

__global__ void zero_norms() {
  int i = blockIdx.x * blockDim.x + threadIdx.x;
  if (i < BNTOT) g_ws_f[OFF_NORMS + i] = 0.f;
}

// ------- split-bf16 into MFMA-fragment-tile layout (points + W5 weights) -------
__global__ void split_kernel(const void* xraw, int lda, int C,
                             int csh2, int dst, int total) {
  int i = blockIdx.x * blockDim.x + threadIdx.x;
  if (i >= total) return;
  const int isb = g_flag;
  int t = i >> 9, win = i & 511;
  int quad = win >> 7, l16 = (win >> 3) & 15, j = win & 7;
  int ktiles_m1 = (1 << csh2) - 1;
  int rg = t >> csh2, kt = t & ktiles_m1;
  int r = rg * 16 + l16;
  int c = kt * 32 + quad * 8 + j;
  float v = (c < C) ? ldany(xraw, (size_t)r * lda + c, isb) : 0.f;
  bf16 h = __float2bfloat16(v);
  float hf = __bfloat162float(h);
  bf16 l = __float2bfloat16(v - hf);
  unsigned short* H = dst ? g_whi : g_hi;
  unsigned short* L = dst ? g_wlo : g_lo;
  H[i] = *(unsigned short*)&h;
  L[i] = *(unsigned short*)&l;
}

// ------- fused KNN (partitioned): MFMA distances + per-partition top-10 -------
// Double-buffered sd: one barrier per tile.
template <int CPAD>
__global__ __launch_bounds__(256) void knn_fused(int N) {
  constexpr int KT = CPAD >> 5;
  __shared__ __align__(16) float sdbuf[2][64 * 68];  // 34816 B
  __shared__ float th[256];                          // [wave][query]
  const int tid = threadIdx.x;
  const int wave = tid >> 6, lane = tid & 63;
  const int quad = lane >> 4, l16 = lane & 15;
  const int b = blockIdx.y;
  const int q0 = blockIdx.x * 64;
  const int part = blockIdx.z;
  const int PN = N / NPART;
  const size_t rowb = (size_t)b * N;
  const float* norms = g_ws_f + OFF_NORMS;

  const int arg = (int)((rowb + q0) >> 4) + wave;
  s8v ah[KT], al[KT];
#pragma unroll
  for (int kt = 0; kt < KT; ++kt) {
    const size_t abase = ((size_t)arg * KT + kt) * 512 + lane * 8;
    ah[kt] = *(const s8v*)(g_hi + abase);
    al[kt] = *(const s8v*)(g_lo + abase);
  }

  const int selfn = q0 + lane;  // this thread maintains query q0+lane
  const float qn = norms[rowb + selfn];
  u64 K[10];
#pragma unroll
  for (int i = 0; i < 10; ++i) K[i] = KINIT;
  th[wave * 64 + lane] = FMAX;  // visible after first in-loop barrier

  int pb = 0;
  for (int m0 = part * PN; m0 < (part + 1) * PN; m0 += 64, pb ^= 1) {
    f32x4 acc[4];
#pragma unroll
    for (int s = 0; s < 4; ++s) acc[s] = (f32x4){0.f, 0.f, 0.f, 0.f};
    const int brg0 = (int)((rowb + m0) >> 4);
#pragma unroll
    for (int kt = 0; kt < KT; ++kt) {
#pragma unroll
      for (int s = 0; s < 4; ++s) {
        const size_t bbase = ((size_t)(brg0 + s) * KT + kt) * 512 + lane * 8;
        s8v bh = *(const s8v*)(g_hi + bbase);
        s8v bl = *(const s8v*)(g_lo + bbase);
        acc[s] = __builtin_amdgcn_mfma_f32_16x16x32_bf16(ah[kt], bh, acc[s], 0, 0, 0);
        acc[s] = __builtin_amdgcn_mfma_f32_16x16x32_bf16(ah[kt], bl, acc[s], 0, 0, 0);
        acc[s] = __builtin_amdgcn_mfma_f32_16x16x32_bf16(al[kt], bh, acc[s], 0, 0, 0);
      }
    }
    // write this tile into buf[pb]; only collides with scans of tile t-2,
    // which all waves finished before passing the previous barrier.
    float* sd = sdbuf[pb];
#pragma unroll
    for (int s = 0; s < 4; ++s) {
      int ml = s * 16 + l16;
      float nm = norms[rowb + m0 + ml];
#pragma unroll
      for (int r = 0; r < 4; ++r)
        sd[(wave * 16 + quad * 4 + r) * 68 + ml] = nm - 2.f * acc[s][r];
    }
    __syncthreads();  // single barrier per tile
    // shared threshold: min over 4 waves (any th value >= final 10th-best)
    const float T = fminf(fminf(th[lane], th[64 + lane]),
                          fminf(th[128 + lane], th[192 + lane]));
    // phase 1: filter d_raw + qn <= T (ties pass; exact u64 in phase 2)
    const int mbase = m0 + wave * 16;
    const float* srow = sd + lane * 68 + wave * 16;
    unsigned pass = 0;
#pragma unroll
    for (int jj = 0; jj < 16; jj += 4) {
      float4 d4 = *(const float4*)(srow + jj);
      pass |= (unsigned)(d4.x + qn <= T) << jj;
      pass |= (unsigned)(d4.y + qn <= T) << (jj + 1);
      pass |= (unsigned)(d4.z + qn <= T) << (jj + 2);
      pass |= (unsigned)(d4.w + qn <= T) << (jj + 3);
    }
    if ((unsigned)(selfn - mbase) < 16u) pass &= ~(1u << (selfn - mbase));
    // phase 2: insert only passing candidates (exact keys)
    while (pass) {
      int jj = __builtin_ctz(pass);
      pass &= pass - 1;
      int m = mbase + jj;
      float d = fmaxf(srow[jj] + qn, 0.f);
      u64 key = ((u64)__float_as_uint(d) << 32) | (unsigned)m;
      if (key < K[9]) {
        bool prev = true;
#pragma unroll
        for (int s2 = 9; s2 >= 1; --s2) {
          bool sh = key < K[s2 - 1];
          K[s2] = sh ? K[s2 - 1] : (prev ? key : K[s2]);
          prev = sh;
        }
        if (prev) K[0] = key;
      }
    }
    th[wave * 64 + lane] = __uint_as_float((unsigned)(K[9] >> 32));
  }
  __syncthreads();  // sd/th dead; reuse sdbuf for merge lists
  u64* mlist = (u64*)sdbuf;
#pragma unroll
  for (int i = 0; i < 10; ++i) mlist[(lane * 4 + wave) * 10 + i] = K[i];
  __syncthreads();
  if (tid < 64) {
    int q = tid;
    int p0 = 0, p1 = 0, p2 = 0, p3 = 0;
    size_t ob = ((rowb + q0 + q) * NPART + part) * 10;
    for (int cnt = 0; cnt < 10; ++cnt) {
      u64 k0 = mlist[(q * 4 + 0) * 10 + p0];
      u64 k1 = mlist[(q * 4 + 1) * 10 + p1];
      u64 k2 = mlist[(q * 4 + 2) * 10 + p2];
      u64 k3 = mlist[(q * 4 + 3) * 10 + p3];
      u64 bk = k0; int bp = 0;
      if (k1 < bk) { bk = k1; bp = 1; }
      if (k2 < bk) { bk = k2; bp = 2; }
      if (k3 < bk) { bk = k3; bp = 3; }
      if (bp == 0) ++p0; else if (bp == 1) ++p1; else if (bp == 2) ++p2; else ++p3;
      g_pk[ob + cnt] = bk;
    }
  }
}

// ------- merge NPART sorted partial lists per query -> final top-10 -------
__global__ void knn_merge() {
  int row = blockIdx.x * blockDim.x + threadIdx.x;
  if (row >= BNTOT) return;
  const u64* pk = g_pk + (size_t)row * NPART * 10;
  int ptr[NPART];
#pragma unroll
  for (int p = 0; p < NPART; ++p) ptr[p] = 0;
  int* ob = g_ws_i + (size_t)row * 10;
  for (int k = 0; k < 10; ++k) {
    u64 bk = ~0ULL; int bp = 0;
#pragma unroll
    for (int p = 0; p < NPART; ++p) {
      u64 key = pk[p * 10 + ptr[p]];
      if (key < bk) { bk = key; bp = p; }
    }
#pragma unroll
    for (int p = 0; p < NPART; ++p) ptr[p] += (p == bp);
    ob[k] = (int)(bk & 0xFFFFFFFFu);
  }
}

// --- G[chunk][z] = X @ W_half^T via MFMA; A from frag-tiled g_hi/g_lo ---
template <int CPAD>
__global__ __launch_bounds__(256) void gmat_mfma(const void* W, int C, int BN) {
  constexpr int KT = CPAD >> 5;
  __shared__ __align__(16) unsigned short wbh[4 * KT * 512];
  __shared__ __align__(16) unsigned short wbl[4 * KT * 512];
  const int isb = g_flag;
  const int tid = threadIdx.x;
  const int wave = tid >> 6, lane = tid & 63;
  const int quad = lane >> 4, l16 = lane & 15;
  const int r0 = blockIdx.x * 64;
  const int chunk = blockIdx.y;
  const int z = blockIdx.z;
  const int o_base = chunk * 64;
  for (int i = tid; i < 4 * KT * 512; i += 256) {
    int t = i >> 9, win = i & 511;
    int q2 = win >> 7, s16 = (win >> 3) & 15, j = win & 7;
    int s = t / KT, kt = t % KT;
    int orow = o_base + s * 16 + s16;
    int c = kt * 32 + q2 * 8 + j;
    float v = (c < C) ? ldany(W, (size_t)orow * (2 * C) + (size_t)z * C + c, isb) : 0.f;
    bf16 h = __float2bfloat16(v);
    float hf = __bfloat162float(h);
    bf16 l = __float2bfloat16(v - hf);
    wbh[i] = *(unsigned short*)&h;
    wbl[i] = *(unsigned short*)&l;
  }
  __syncthreads();
  f32x4 acc[4];
#pragma unroll
  for (int s = 0; s < 4; ++s) acc[s] = (f32x4){0.f, 0.f, 0.f, 0.f};
  const int arg = (r0 >> 4) + wave;
#pragma unroll
  for (int kt = 0; kt < KT; ++kt) {
    const size_t abase = ((size_t)arg * KT + kt) * 512 + lane * 8;
    s8v ah = *(const s8v*)(g_hi + abase);
    s8v al = *(const s8v*)(g_lo + abase);
#pragma unroll
    for (int s = 0; s < 4; ++s) {
      const int woff = (s * KT + kt) * 512 + lane * 8;
      s8v bh = *(const s8v*)(wbh + woff);
      s8v bl = *(const s8v*)(wbl + woff);
      acc[s] = __builtin_amdgcn_mfma_f32_16x16x32_bf16(ah, bh, acc[s], 0, 0, 0);
      acc[s] = __builtin_amdgcn_mfma_f32_16x16x32_bf16(ah, bl, acc[s], 0, 0, 0);
      acc[s] = __builtin_amdgcn_mfma_f32_16x16x32_bf16(al, bh, acc[s], 0, 0, 0);
    }
  }
  float* Gz = g_G + (size_t)(chunk * 2 + z) * BN * 64;
#pragma unroll
  for (int s = 0; s < 4; ++s)
#pragma unroll
    for (int r = 0; r < 4; ++r)
      Gz[(size_t)(r0 + wave * 16 + quad * 4 + r) * 64 + s * 16 + l16] = acc[s][r];
}

// ------- edge-conv epilogue: gather+max, then fused splits + norms -------
__global__ void edge_epi64(const void* s, const void* t, int colbase,
                           int knn_csh2, int norms_mode, int BN, int N) {
  const int isb = g_flag;
  int tid = threadIdx.x;
  int p = tid >> 6, o = tid & 63;
  int row = blockIdx.x * 4 + p;
  int chunk = blockIdx.y;
  const float* G1 = g_G + (size_t)(chunk * 2 + 0) * BN * 64;
  const float* G2 = g_G + (size_t)(chunk * 2 + 1) * BN * 64;
  int b = row / N;
  const int* id = g_ws_i + (size_t)row * 10;
  float g1n = G1[(size_t)row * 64 + o];
  float base = G2[(size_t)row * 64 + o] - g1n;
  int co = chunk * 64 + o;
  float sv = ldany(s, co, isb), tv = ldany(t, co, isb);
  float mx = -FMAX;
#pragma unroll
  for (int k = 0; k < 10; ++k) {
    int m = id[k];
    m = (m < 0) ? 0 : ((m >= N) ? N - 1 : m);
    float h = sv * (G1[((size_t)b * N + m) * 64 + o] + base) + tv;
    h = (h >= 0.f) ? h : NEG * h;
    mx = fmaxf(mx, h);
  }
  bf16 h16 = __float2bfloat16(mx);
  float hf = __bfloat162float(h16);
  bf16 l16v = __float2bfloat16(mx - hf);
  unsigned short hu = *(unsigned short*)&h16;
  unsigned short lu = *(unsigned short*)&l16v;
  if (knn_csh2 >= 0) {
    int KTL = 1 << knn_csh2;
    size_t ki = ((size_t)(row >> 4) * KTL + (co >> 5)) * 512 +
                ((size_t)((co >> 3) & 3)) * 128 + (row & 15) * 8 + (co & 7);
    g_hi[ki] = hu; g_lo[ki] = lu;
  }
  {
    int gc = colbase + co;
    size_t wi = ((size_t)(row >> 4) * 16 + (gc >> 5)) * 512 +
                ((size_t)((gc >> 3) & 3)) * 128 + (row & 15) * 8 + (gc & 7);
    g_xhi5[wi] = hu; g_xlo5[wi] = lu;
  }
  if (norms_mode) {
    float ns = mx * mx;
#pragma unroll
    for (int off = 32; off > 0; off >>= 1) ns += __shfl_down(ns, off, 64);
    if (o == 0) {
      if (norms_mode == 1) g_ws_f[OFF_NORMS + row] = ns;
      else atomicAdd(&g_ws_f[OFF_NORMS + row], ns);
    }
  }
}

// ------- W5 MFMA + max over n; wave tile 32n x 64o (s5>0: affine after max) ----
__global__ __launch_bounds__(256) void w5max_mfma(const void* s5, const void* t5, int N) {
  const int tid = threadIdx.x;
  const int wave = tid >> 6, lane = tid & 63;
  const int quad = lane >> 4, l16 = lane & 15;
  const int b = blockIdx.z;
  const int o0 = blockIdx.y * 64, n0 = blockIdx.x * 128;
  f32x4 acc[2][4];
#pragma unroll
  for (int a = 0; a < 2; ++a)
#pragma unroll
    for (int s = 0; s < 4; ++s) acc[a][s] = (f32x4){0.f, 0.f, 0.f, 0.f};

  const int arg0 = (int)(((size_t)b * N + n0) >> 4) + wave * 2;
  const int wrg0 = o0 >> 4;
#pragma unroll 2
  for (int kt = 0; kt < 16; ++kt) {
    s8v ah[2], al[2];
#pragma unroll
    for (int a = 0; a < 2; ++a) {
      const size_t abase = ((size_t)(arg0 + a) * 16 + kt) * 512 + lane * 8;
      ah[a] = *(const s8v*)(g_xhi5 + abase);
      al[a] = *(const s8v*)(g_xlo5 + abase);
    }
#pragma unroll
    for (int s = 0; s < 4; ++s) {
      const size_t bbase = ((size_t)(wrg0 + s) * 16 + kt) * 512 + lane * 8;
      s8v bh = *(const s8v*)(g_whi + bbase);
      s8v bl = *(const s8v*)(g_wlo + bbase);
#pragma unroll
      for (int a = 0; a < 2; ++a) {
        acc[a][s] = __builtin_amdgcn_mfma_f32_16x16x32_bf16(ah[a], bh, acc[a][s], 0, 0, 0);
        acc[a][s] = __builtin_amdgcn_mfma_f32_16x16x32_bf16(ah[a], bl, acc[a][s], 0, 0, 0);
        acc[a][s] = __builtin_amdgcn_mfma_f32_16x16x32_bf16(al[a], bh, acc[a][s], 0, 0, 0);
      }
    }
  }
  __shared__ float red[4][64];
  const int isb = g_flag;
#pragma unroll
  for (int s = 0; s < 4; ++s) {
    float m4 = -FMAX;
#pragma unroll
    for (int a = 0; a < 2; ++a)
#pragma unroll
      for (int r = 0; r < 4; ++r) m4 = fmaxf(m4, acc[a][s][r]);
#pragma unroll
    for (int off = 16; off < 64; off <<= 1) m4 = fmaxf(m4, __shfl_down(m4, off, 64));
    if (quad == 0) red[wave][s * 16 + l16] = m4;
  }
  __syncthreads();
  if (tid < 64) {
    float m = fmaxf(fmaxf(red[0][tid], red[1][tid]), fmaxf(red[2][tid], red[3][tid]));
    int o = o0 + tid;
    float sv = ldany(s5, o, isb), tv = ldany(t5, o, isb);
    float h = sv * m + tv;
    h = (h >= 0.f) ? h : NEG * h;
    g_ws_f[OFF_PART + ((size_t)b * 1024 + o) * 16 + blockIdx.x] = h;
  }
}

__global__ void poolred_kernel() {
  const float* part = g_ws_f + OFF_PART;
  float* pooled = g_ws_f + OFF_POOLED;
  int i = blockIdx.x * blockDim.x + threadIdx.x;
  if (i >= 8 * 1024) return;
  const float* p = part + (size_t)i * 16;
  float m = -FMAX;
#pragma unroll
  for (int j = 0; j < 16; ++j) m = fmaxf(m, p[j]);
  pooled[i] = m;
}

// ---------------- FC: one wave per output ----------------
__global__ void fc_kernel(size_t inoff, const void* W, const void* bias,
                          const void* s, const void* t, size_t outoff, int has_out,
                          void* OUTB, int Bb, int IC, int OC, int act) {
  const int isb = g_flag;
  const float* IN = g_ws_f + inoff;
  int gw = (blockIdx.x * blockDim.x + threadIdx.x) >> 6;
  int lane = threadIdx.x & 63;
  if (gw >= Bb * OC) return;
  int b = gw / OC, o = gw % OC;
  const float* in = IN + (size_t)b * IC;
  float acc = 0.f;
  for (int c = lane; c < IC; c += 64) acc += in[c] * ldany(W, (size_t)o * IC + c, isb);
#pragma unroll
  for (int off = 32; off > 0; off >>= 1) acc += __shfl_down(acc, off, 64);
  if (lane == 0) {
    float h = acc;
    if (bias) h += ldany(bias, o, isb);
    if (s) h = h * ldany(s, o, isb) + ldany(t, o, isb);
    if (act) h = (h >= 0.f) ? h : NEG * h;
    if (has_out) g_ws_f[outoff + (size_t)b * OC + o] = h;
    if (OUTB) {
      if (isb) ((bf16*)OUTB)[(size_t)b * OC + o] = __float2bfloat16(h);
      else ((float*)OUTB)[(size_t)b * OC + o] = h;
    }
  }
}

extern "C" void kernel_launch(void* const* d_in, const int* in_sizes, int n_in,
                              void* d_out, int out_size, void* d_ws, size_t ws_size,
                              hipStream_t stream) {
  const int B = 8, N = 2048, BN = B * N;
  const void* points = d_in[0];
  const void *W1 = d_in[1], *s1 = d_in[2], *t1 = d_in[3];
  const void *W2 = d_in[4], *s2 = d_in[5], *t2 = d_in[6];
  const void *W3 = d_in[7], *s3 = d_in[8], *t3 = d_in[9];
  const void *W4 = d_in[10], *s4 = d_in[11], *t4 = d_in[12];
  const void *W5 = d_in[13], *s5 = d_in[14], *t5 = d_in[15];
  const void *Wf1 = d_in[16], *sf1 = d_in[17], *tf1 = d_in[18];
  const void *Wf2 = d_in[19], *bf2 = d_in[20], *sf2 = d_in[21], *tf2 = d_in[22];
  const void *Wf3 = d_in[23], *bf3 = d_in[24];

  probe_kernel<<<1, 1, 0, stream>>>(points);
  split_kernel<<<(1024 * 512) / 256, 256, 0, stream>>>(W5, 512, 512, 4, 1, 1024 * 512);

  // ---- layer 1: points (C=3, CPAD=32) -> cols 0:64
  norms_kernel<<<BN / 4, 256, 0, stream>>>(points, 3, 3, BN);
  split_kernel<<<(BN * 32) / 256, 256, 0, stream>>>(points, 3, 3, 0, 0, BN * 32);
  knn_fused<32><<<dim3(N / 64, B, NPART), 256, 0, stream>>>(N);
  knn_merge<<<BN / 256, 256, 0, stream>>>();
  gmat_mfma<32><<<dim3(BN / 64, 1, 2), 256, 0, stream>>>(W1, 3, BN);
  edge_epi64<<<dim3(BN / 4, 1), 256, 0, stream>>>(s1, t1, 0, 1, 1, BN, N);
  // ---- layer 2: (C=64, CPAD=64) -> cols 64:128
  knn_fused<64><<<dim3(N / 64, B, NPART), 256, 0, stream>>>(N);
  knn_merge<<<BN / 256, 256, 0, stream>>>();
  gmat_mfma<64><<<dim3(BN / 64, 1, 2), 256, 0, stream>>>(W2, 64, BN);
  edge_epi64<<<dim3(BN / 4, 1), 256, 0, stream>>>(s2, t2, 64, 1, 1, BN, N);
  // ---- layer 3: (C=64) -> cols 128:256, 2 chunks; next layer CPAD=128
  knn_fused<64><<<dim3(N / 64, B, NPART), 256, 0, stream>>>(N);
  knn_merge<<<BN / 256, 256, 0, stream>>>();
  gmat_mfma<64><<<dim3(BN / 64, 2, 2), 256, 0, stream>>>(W3, 64, BN);
  zero_norms<<<BN / 256, 256, 0, stream>>>();
  edge_epi64<<<dim3(BN / 4, 2), 256, 0, stream>>>(s3, t3, 128, 2, 2, BN, N);
  // ---- layer 4: (C=128) -> cols 256:512, 4 chunks; no next knn
  knn_fused<128><<<dim3(N / 64, B, NPART), 256, 0, stream>>>(N);
  knn_merge<<<BN / 256, 256, 0, stream>>>();
  gmat_mfma<128><<<dim3(BN / 64, 4, 2), 256, 0, stream>>>(W4, 128, BN);
  edge_epi64<<<dim3(BN / 4, 4), 256, 0, stream>>>(s4, t4, 256, -1, 0, BN, N);
  // ---- W5 + global max pool
  w5max_mfma<<<dim3(16, 16, 8), 256, 0, stream>>>(s5, t5, N);
  poolred_kernel<<<32, 256, 0, stream>>>();
  // ---- FC head
  fc_kernel<<<(8 * 512 * 64) / 256, 256, 0, stream>>>(OFF_POOLED, Wf1, nullptr, sf1, tf1, OFF_H1, 1, nullptr, 8, 1024, 512, 1);
  fc_kernel<<<(8 * 256 * 64) / 256, 256, 0, stream>>>(OFF_H1, Wf2, bf2, sf2, tf2, OFF_H2, 1, nullptr, 8, 512, 256, 1);
  fc_kernel<<<6, 256, 0, stream>>>(OFF_H2, Wf3, bf3, nullptr, nullptr, 0, 0, d_out, 8, 256, 3, 0);
}

// Round 17
// 597.599 us; speedup vs baseline: 1.1584x; 1.0257x over previous
//
#include <hip/hip_runtime.h>
#include <hip/hip_bf16.h>

// DGCNN-style KNN classifier. B=8, N=2048, K=10.
// g_flag=1 -> bf16 inputs, 0 -> fp32 (runtime probe). Output same dtype.
// Scratch in static __device__ globals; every byte read is written earlier in
// the same launch (graph-replay safe; layer-3 norms re-zeroed before atomics).
//
// R16->R17: (1) w5max wave tile 32nx64o -> 64nx64o (loads/MFMA 0.5 -> 0.33;
// was load-issue bound). (2) knn_merge folded into edge_epi64 as a parallel
// rank-select over the 40 partial keys (lanes 0-39, rank = #smaller, keys
// unique -> exact top-10 in order; wave-internal LDS, no barriers). -4
// dispatches, g_ws_i eliminated.

#define NEG 0.2f
#define FMAX 3.402823466e+38f
#define KINIT 0x7F7FFFFFFFFFFFFFull  // (FLT_MAX bits << 32) | 0xFFFFFFFF

typedef __hip_bfloat16 bf16;
typedef __attribute__((ext_vector_type(8))) short s8v;    // 8 bf16
typedef __attribute__((ext_vector_type(4))) float f32x4;  // MFMA acc
typedef unsigned long long u64;

#define BB 8
#define NN 2048
#define BNTOT (BB * NN)
#define NPART 4

#define OFF_NORMS ((size_t)0)
#define OFF_PART (OFF_NORMS + BNTOT)
#define OFF_POOLED (OFF_PART + 8 * 1024 * 32)
#define OFF_H1 (OFF_POOLED + 8 * 1024)
#define OFF_H2 (OFF_H1 + 8 * 512)
#define WSF_TOTAL (OFF_H2 + 8 * 256)

__device__ float g_ws_f[WSF_TOTAL];
__device__ float g_G[(size_t)8 * BNTOT * 64];     // [chunk(<=4)][z(2)][BN][64]
__device__ u64 g_pk[(size_t)BNTOT * NPART * 10];  // partial top-10 packed keys
__device__ int g_flag;                            // 1 = bf16 inputs, 0 = fp32
__device__ unsigned short g_hi[(size_t)BNTOT * 512];    // knn/gmat split (frag-tiled)
__device__ unsigned short g_lo[(size_t)BNTOT * 512];
__device__ unsigned short g_xhi5[(size_t)BNTOT * 512];  // W5-layout activations
__device__ unsigned short g_xlo5[(size_t)BNTOT * 512];
__device__ unsigned short g_whi[1024 * 512];            // split W5 weights
__device__ unsigned short g_wlo[1024 * 512];

__device__ __forceinline__ float ldany(const void* p, size_t i, int isb) {
  if (isb) return __bfloat162float(((const bf16*)p)[i]);
  return ((const float*)p)[i];
}

// ---------------- dtype probe ----------------
__global__ void probe_kernel(const void* pts) {
  const unsigned* w = (const unsigned*)pts;
  int cnt = 0;
  for (int i = 0; i < 256; ++i) {
    unsigned e2 = (w[i] >> 7) & 0xFF;
    cnt += (e2 >= 110 && e2 <= 135);
  }
  g_flag = (cnt > 128) ? 1 : 0;
}

// ---------------- norms (layer-1 input only) ----------------
__global__ void norms_kernel(const void* xraw, int lda, int C, int BN) {
  const int isb = g_flag;
  float* norms = g_ws_f + OFF_NORMS;
  int row = blockIdx.x * (blockDim.x >> 6) + (threadIdx.x >> 6);
  int lane = threadIdx.x & 63;
  if (row >= BN) return;
  float s = 0.f;
  for (int c = lane; c < C; c += 64) {
    float v = ldany(xraw, (size_t)row * lda + c, isb);
    s += v * v;
  }
#pragma unroll
  for (int off = 32; off > 0; off >>= 1) s += __shfl_down(s, off, 64);
  if (lane == 0) norms[row] = s;
}

__global__ void zero_norms() {
  int i = blockIdx.x * blockDim.x + threadIdx.x;
  if (i < BNTOT) g_ws_f[OFF_NORMS + i] = 0.f;
}

// ------- split-bf16 into MFMA-fragment-tile layout (points + W5 weights) -------
__global__ void split_kernel(const void* xraw, int lda, int C,
                             int csh2, int dst, int total) {
  int i = blockIdx.x * blockDim.x + threadIdx.x;
  if (i >= total) return;
  const int isb = g_flag;
  int t = i >> 9, win = i & 511;
  int quad = win >> 7, l16 = (win >> 3) & 15, j = win & 7;
  int ktiles_m1 = (1 << csh2) - 1;
  int rg = t >> csh2, kt = t & ktiles_m1;
  int r = rg * 16 + l16;
  int c = kt * 32 + quad * 8 + j;
  float v = (c < C) ? ldany(xraw, (size_t)r * lda + c, isb) : 0.f;
  bf16 h = __float2bfloat16(v);
  float hf = __bfloat162float(h);
  bf16 l = __float2bfloat16(v - hf);
  unsigned short* H = dst ? g_whi : g_hi;
  unsigned short* L = dst ? g_wlo : g_lo;
  H[i] = *(unsigned short*)&h;
  L[i] = *(unsigned short*)&l;
}

// ------- fused KNN (partitioned): MFMA distances + per-partition top-10 -------
// Double-buffered sd: one barrier per tile.
template <int CPAD>
__global__ __launch_bounds__(256) void knn_fused(int N) {
  constexpr int KT = CPAD >> 5;
  __shared__ __align__(16) float sdbuf[2][64 * 68];  // 34816 B
  __shared__ float th[256];                          // [wave][query]
  const int tid = threadIdx.x;
  const int wave = tid >> 6, lane = tid & 63;
  const int quad = lane >> 4, l16 = lane & 15;
  const int b = blockIdx.y;
  const int q0 = blockIdx.x * 64;
  const int part = blockIdx.z;
  const int PN = N / NPART;
  const size_t rowb = (size_t)b * N;
  const float* norms = g_ws_f + OFF_NORMS;

  const int arg = (int)((rowb + q0) >> 4) + wave;
  s8v ah[KT], al[KT];
#pragma unroll
  for (int kt = 0; kt < KT; ++kt) {
    const size_t abase = ((size_t)arg * KT + kt) * 512 + lane * 8;
    ah[kt] = *(const s8v*)(g_hi + abase);
    al[kt] = *(const s8v*)(g_lo + abase);
  }

  const int selfn = q0 + lane;  // this thread maintains query q0+lane
  const float qn = norms[rowb + selfn];
  u64 K[10];
#pragma unroll
  for (int i = 0; i < 10; ++i) K[i] = KINIT;
  th[wave * 64 + lane] = FMAX;  // visible after first in-loop barrier

  int pb = 0;
  for (int m0 = part * PN; m0 < (part + 1) * PN; m0 += 64, pb ^= 1) {
    f32x4 acc[4];
#pragma unroll
    for (int s = 0; s < 4; ++s) acc[s] = (f32x4){0.f, 0.f, 0.f, 0.f};
    const int brg0 = (int)((rowb + m0) >> 4);
#pragma unroll
    for (int kt = 0; kt < KT; ++kt) {
#pragma unroll
      for (int s = 0; s < 4; ++s) {
        const size_t bbase = ((size_t)(brg0 + s) * KT + kt) * 512 + lane * 8;
        s8v bh = *(const s8v*)(g_hi + bbase);
        s8v bl = *(const s8v*)(g_lo + bbase);
        acc[s] = __builtin_amdgcn_mfma_f32_16x16x32_bf16(ah[kt], bh, acc[s], 0, 0, 0);
        acc[s] = __builtin_amdgcn_mfma_f32_16x16x32_bf16(ah[kt], bl, acc[s], 0, 0, 0);
        acc[s] = __builtin_amdgcn_mfma_f32_16x16x32_bf16(al[kt], bh, acc[s], 0, 0, 0);
      }
    }
    float* sd = sdbuf[pb];
#pragma unroll
    for (int s = 0; s < 4; ++s) {
      int ml = s * 16 + l16;
      float nm = norms[rowb + m0 + ml];
#pragma unroll
      for (int r = 0; r < 4; ++r)
        sd[(wave * 16 + quad * 4 + r) * 68 + ml] = nm - 2.f * acc[s][r];
    }
    __syncthreads();  // single barrier per tile
    const float T = fminf(fminf(th[lane], th[64 + lane]),
                          fminf(th[128 + lane], th[192 + lane]));
    const int mbase = m0 + wave * 16;
    const float* srow = sd + lane * 68 + wave * 16;
    unsigned pass = 0;
#pragma unroll
    for (int jj = 0; jj < 16; jj += 4) {
      float4 d4 = *(const float4*)(srow + jj);
      pass |= (unsigned)(d4.x + qn <= T) << jj;
      pass |= (unsigned)(d4.y + qn <= T) << (jj + 1);
      pass |= (unsigned)(d4.z + qn <= T) << (jj + 2);
      pass |= (unsigned)(d4.w + qn <= T) << (jj + 3);
    }
    if ((unsigned)(selfn - mbase) < 16u) pass &= ~(1u << (selfn - mbase));
    while (pass) {
      int jj = __builtin_ctz(pass);
      pass &= pass - 1;
      int m = mbase + jj;
      float d = fmaxf(srow[jj] + qn, 0.f);
      u64 key = ((u64)__float_as_uint(d) << 32) | (unsigned)m;
      if (key < K[9]) {
        bool prev = true;
#pragma unroll
        for (int s2 = 9; s2 >= 1; --s2) {
          bool sh = key < K[s2 - 1];
          K[s2] = sh ? K[s2 - 1] : (prev ? key : K[s2]);
          prev = sh;
        }
        if (prev) K[0] = key;
      }
    }
    th[wave * 64 + lane] = __uint_as_float((unsigned)(K[9] >> 32));
  }
  __syncthreads();  // sd/th dead; reuse sdbuf for merge lists
  u64* mlist = (u64*)sdbuf;
#pragma unroll
  for (int i = 0; i < 10; ++i) mlist[(lane * 4 + wave) * 10 + i] = K[i];
  __syncthreads();
  if (tid < 64) {
    int q = tid;
    int p0 = 0, p1 = 0, p2 = 0, p3 = 0;
    size_t ob = ((rowb + q0 + q) * NPART + part) * 10;
    for (int cnt = 0; cnt < 10; ++cnt) {
      u64 k0 = mlist[(q * 4 + 0) * 10 + p0];
      u64 k1 = mlist[(q * 4 + 1) * 10 + p1];
      u64 k2 = mlist[(q * 4 + 2) * 10 + p2];
      u64 k3 = mlist[(q * 4 + 3) * 10 + p3];
      u64 bk = k0; int bp = 0;
      if (k1 < bk) { bk = k1; bp = 1; }
      if (k2 < bk) { bk = k2; bp = 2; }
      if (k3 < bk) { bk = k3; bp = 3; }
      if (bp == 0) ++p0; else if (bp == 1) ++p1; else if (bp == 2) ++p2; else ++p3;
      g_pk[ob + cnt] = bk;
    }
  }
}

// --- G[chunk][z] = X @ W_half^T via MFMA; A from frag-tiled g_hi/g_lo ---
template <int CPAD>
__global__ __launch_bounds__(256) void gmat_mfma(const void* W, int C, int BN) {
  constexpr int KT = CPAD >> 5;
  __shared__ __align__(16) unsigned short wbh[4 * KT * 512];
  __shared__ __align__(16) unsigned short wbl[4 * KT * 512];
  const int isb = g_flag;
  const int tid = threadIdx.x;
  const int wave = tid >> 6, lane = tid & 63;
  const int quad = lane >> 4, l16 = lane & 15;
  const int r0 = blockIdx.x * 64;
  const int chunk = blockIdx.y;
  const int z = blockIdx.z;
  const int o_base = chunk * 64;
  for (int i = tid; i < 4 * KT * 512; i += 256) {
    int t = i >> 9, win = i & 511;
    int q2 = win >> 7, s16 = (win >> 3) & 15, j = win & 7;
    int s = t / KT, kt = t % KT;
    int orow = o_base + s * 16 + s16;
    int c = kt * 32 + q2 * 8 + j;
    float v = (c < C) ? ldany(W, (size_t)orow * (2 * C) + (size_t)z * C + c, isb) : 0.f;
    bf16 h = __float2bfloat16(v);
    float hf = __bfloat162float(h);
    bf16 l = __float2bfloat16(v - hf);
    wbh[i] = *(unsigned short*)&h;
    wbl[i] = *(unsigned short*)&l;
  }
  __syncthreads();
  f32x4 acc[4];
#pragma unroll
  for (int s = 0; s < 4; ++s) acc[s] = (f32x4){0.f, 0.f, 0.f, 0.f};
  const int arg = (r0 >> 4) + wave;
#pragma unroll
  for (int kt = 0; kt < KT; ++kt) {
    const size_t abase = ((size_t)arg * KT + kt) * 512 + lane * 8;
    s8v ah = *(const s8v*)(g_hi + abase);
    s8v al = *(const s8v*)(g_lo + abase);
#pragma unroll
    for (int s = 0; s < 4; ++s) {
      const int woff = (s * KT + kt) * 512 + lane * 8;
      s8v bh = *(const s8v*)(wbh + woff);
      s8v bl = *(const s8v*)(wbl + woff);
      acc[s] = __builtin_amdgcn_mfma_f32_16x16x32_bf16(ah, bh, acc[s], 0, 0, 0);
      acc[s] = __builtin_amdgcn_mfma_f32_16x16x32_bf16(ah, bl, acc[s], 0, 0, 0);
      acc[s] = __builtin_amdgcn_mfma_f32_16x16x32_bf16(al, bh, acc[s], 0, 0, 0);
    }
  }
  float* Gz = g_G + (size_t)(chunk * 2 + z) * BN * 64;
#pragma unroll
  for (int s = 0; s < 4; ++s)
#pragma unroll
    for (int r = 0; r < 4; ++r)
      Gz[(size_t)(r0 + wave * 16 + quad * 4 + r) * 64 + s * 16 + l16] = acc[s][r];
}

// ------- edge-conv epilogue: inline NPART-merge (rank-select) + gather+max
//         + fused splits + norms. One wave per row; wave-internal LDS only.
__global__ void edge_epi64(const void* s, const void* t, int colbase,
                           int knn_csh2, int norms_mode, int BN, int N) {
  __shared__ u64 kbuf[4][40];
  __shared__ int oidx[4][10];
  const int isb = g_flag;
  int tid = threadIdx.x;
  int p = tid >> 6, o = tid & 63;  // p = wave = row-in-block
  int row = blockIdx.x * 4 + p;
  int chunk = blockIdx.y;
  const float* G1 = g_G + (size_t)(chunk * 2 + 0) * BN * 64;
  const float* G2 = g_G + (size_t)(chunk * 2 + 1) * BN * 64;
  int b = row / N;
  // parallel rank-select over the 40 partial keys (keys unique; exact)
  if (o < 40) kbuf[p][o] = g_pk[(size_t)row * 40 + o];
  // wave-internal LDS: same instruction stream orders write->read via waitcnt
  if (o < 40) {
    u64 myk = kbuf[p][o];
    int rank = 0;
#pragma unroll 8
    for (int j = 0; j < 40; ++j) rank += (kbuf[p][j] < myk);
    if (rank < 10) oidx[p][rank] = (int)(myk & 0xFFFFFFFFu);
  }
  float g1n = G1[(size_t)row * 64 + o];
  float base = G2[(size_t)row * 64 + o] - g1n;
  int co = chunk * 64 + o;
  float sv = ldany(s, co, isb), tv = ldany(t, co, isb);
  float mx = -FMAX;
#pragma unroll
  for (int k = 0; k < 10; ++k) {
    int m = oidx[p][k];
    m = (m < 0) ? 0 : ((m >= N) ? N - 1 : m);
    float h = sv * (G1[((size_t)b * N + m) * 64 + o] + base) + tv;
    h = (h >= 0.f) ? h : NEG * h;
    mx = fmaxf(mx, h);
  }
  bf16 h16 = __float2bfloat16(mx);
  float hf = __bfloat162float(h16);
  bf16 l16v = __float2bfloat16(mx - hf);
  unsigned short hu = *(unsigned short*)&h16;
  unsigned short lu = *(unsigned short*)&l16v;
  if (knn_csh2 >= 0) {
    int KTL = 1 << knn_csh2;
    size_t ki = ((size_t)(row >> 4) * KTL + (co >> 5)) * 512 +
                ((size_t)((co >> 3) & 3)) * 128 + (row & 15) * 8 + (co & 7);
    g_hi[ki] = hu; g_lo[ki] = lu;
  }
  {
    int gc = colbase + co;
    size_t wi = ((size_t)(row >> 4) * 16 + (gc >> 5)) * 512 +
                ((size_t)((gc >> 3) & 3)) * 128 + (row & 15) * 8 + (gc & 7);
    g_xhi5[wi] = hu; g_xlo5[wi] = lu;
  }
  if (norms_mode) {
    float ns = mx * mx;
#pragma unroll
    for (int off = 32; off > 0; off >>= 1) ns += __shfl_down(ns, off, 64);
    if (o == 0) {
      if (norms_mode == 1) g_ws_f[OFF_NORMS + row] = ns;
      else atomicAdd(&g_ws_f[OFF_NORMS + row], ns);
    }
  }
}

// ------- W5 MFMA + max over n; wave tile 64n x 64o (s5>0: affine after max) ----
__global__ __launch_bounds__(256) void w5max_mfma(const void* s5, const void* t5, int N) {
  const int tid = threadIdx.x;
  const int wave = tid >> 6, lane = tid & 63;
  const int quad = lane >> 4, l16 = lane & 15;
  const int b = blockIdx.z;
  const int o0 = blockIdx.y * 64, n0 = blockIdx.x * 256;
  f32x4 acc[4][4];
#pragma unroll
  for (int a = 0; a < 4; ++a)
#pragma unroll
    for (int s = 0; s < 4; ++s) acc[a][s] = (f32x4){0.f, 0.f, 0.f, 0.f};

  const int arg0 = (int)(((size_t)b * N + n0) >> 4) + wave * 4;  // 4 row-groups/wave
  const int wrg0 = o0 >> 4;
  for (int kt = 0; kt < 16; ++kt) {
    s8v ah[4], al[4];
#pragma unroll
    for (int a = 0; a < 4; ++a) {
      const size_t abase = ((size_t)(arg0 + a) * 16 + kt) * 512 + lane * 8;
      ah[a] = *(const s8v*)(g_xhi5 + abase);
      al[a] = *(const s8v*)(g_xlo5 + abase);
    }
#pragma unroll
    for (int s = 0; s < 4; ++s) {
      const size_t bbase = ((size_t)(wrg0 + s) * 16 + kt) * 512 + lane * 8;
      s8v bh = *(const s8v*)(g_whi + bbase);
      s8v bl = *(const s8v*)(g_wlo + bbase);
#pragma unroll
      for (int a = 0; a < 4; ++a) {
        acc[a][s] = __builtin_amdgcn_mfma_f32_16x16x32_bf16(ah[a], bh, acc[a][s], 0, 0, 0);
        acc[a][s] = __builtin_amdgcn_mfma_f32_16x16x32_bf16(ah[a], bl, acc[a][s], 0, 0, 0);
        acc[a][s] = __builtin_amdgcn_mfma_f32_16x16x32_bf16(al[a], bh, acc[a][s], 0, 0, 0);
      }
    }
  }
  __shared__ float red[4][64];
  const int isb = g_flag;
#pragma unroll
  for (int s = 0; s < 4; ++s) {
    float m4 = -FMAX;
#pragma unroll
    for (int a = 0; a < 4; ++a)
#pragma unroll
      for (int r = 0; r < 4; ++r) m4 = fmaxf(m4, acc[a][s][r]);
#pragma unroll
    for (int off = 16; off < 64; off <<= 1) m4 = fmaxf(m4, __shfl_down(m4, off, 64));
    if (quad == 0) red[wave][s * 16 + l16] = m4;
  }
  __syncthreads();
  if (tid < 64) {
    float m = fmaxf(fmaxf(red[0][tid], red[1][tid]), fmaxf(red[2][tid], red[3][tid]));
    int o = o0 + tid;
    float sv = ldany(s5, o, isb), tv = ldany(t5, o, isb);
    float h = sv * m + tv;
    h = (h >= 0.f) ? h : NEG * h;
    g_ws_f[OFF_PART + ((size_t)b * 1024 + o) * 8 + blockIdx.x] = h;
  }
}

__global__ void poolred_kernel() {
  const float* part = g_ws_f + OFF_PART;
  float* pooled = g_ws_f + OFF_POOLED;
  int i = blockIdx.x * blockDim.x + threadIdx.x;
  if (i >= 8 * 1024) return;
  const float* p = part + (size_t)i * 8;
  float m = -FMAX;
#pragma unroll
  for (int j = 0; j < 8; ++j) m = fmaxf(m, p[j]);
  pooled[i] = m;
}

// ---------------- FC: one wave per output ----------------
__global__ void fc_kernel(size_t inoff, const void* W, const void* bias,
                          const void* s, const void* t, size_t outoff, int has_out,
                          void* OUTB, int Bb, int IC, int OC, int act) {
  const int isb = g_flag;
  const float* IN = g_ws_f + inoff;
  int gw = (blockIdx.x * blockDim.x + threadIdx.x) >> 6;
  int lane = threadIdx.x & 63;
  if (gw >= Bb * OC) return;
  int b = gw / OC, o = gw % OC;
  const float* in = IN + (size_t)b * IC;
  float acc = 0.f;
  for (int c = lane; c < IC; c += 64) acc += in[c] * ldany(W, (size_t)o * IC + c, isb);
#pragma unroll
  for (int off = 32; off > 0; off >>= 1) acc += __shfl_down(acc, off, 64);
  if (lane == 0) {
    float h = acc;
    if (bias) h += ldany(bias, o, isb);
    if (s) h = h * ldany(s, o, isb) + ldany(t, o, isb);
    if (act) h = (h >= 0.f) ? h : NEG * h;
    if (has_out) g_ws_f[outoff + (size_t)b * OC + o] = h;
    if (OUTB) {
      if (isb) ((bf16*)OUTB)[(size_t)b * OC + o] = __float2bfloat16(h);
      else ((float*)OUTB)[(size_t)b * OC + o] = h;
    }
  }
}

extern "C" void kernel_launch(void* const* d_in, const int* in_sizes, int n_in,
                              void* d_out, int out_size, void* d_ws, size_t ws_size,
                              hipStream_t stream) {
  const int B = 8, N = 2048, BN = B * N;
  const void* points = d_in[0];
  const void *W1 = d_in[1], *s1 = d_in[2], *t1 = d_in[3];
  const void *W2 = d_in[4], *s2 = d_in[5], *t2 = d_in[6];
  const void *W3 = d_in[7], *s3 = d_in[8], *t3 = d_in[9];
  const void *W4 = d_in[10], *s4 = d_in[11], *t4 = d_in[12];
  const void *W5 = d_in[13], *s5 = d_in[14], *t5 = d_in[15];
  const void *Wf1 = d_in[16], *sf1 = d_in[17], *tf1 = d_in[18];
  const void *Wf2 = d_in[19], *bf2 = d_in[20], *sf2 = d_in[21], *tf2 = d_in[22];
  const void *Wf3 = d_in[23], *bf3 = d_in[24];

  probe_kernel<<<1, 1, 0, stream>>>(points);
  split_kernel<<<(1024 * 512) / 256, 256, 0, stream>>>(W5, 512, 512, 4, 1, 1024 * 512);

  // ---- layer 1: points (C=3, CPAD=32) -> cols 0:64
  norms_kernel<<<BN / 4, 256, 0, stream>>>(points, 3, 3, BN);
  split_kernel<<<(BN * 32) / 256, 256, 0, stream>>>(points, 3, 3, 0, 0, BN * 32);
  knn_fused<32><<<dim3(N / 64, B, NPART), 256, 0, stream>>>(N);
  gmat_mfma<32><<<dim3(BN / 64, 1, 2), 256, 0, stream>>>(W1, 3, BN);
  edge_epi64<<<dim3(BN / 4, 1), 256, 0, stream>>>(s1, t1, 0, 1, 1, BN, N);
  // ---- layer 2: (C=64, CPAD=64) -> cols 64:128
  knn_fused<64><<<dim3(N / 64, B, NPART), 256, 0, stream>>>(N);
  gmat_mfma<64><<<dim3(BN / 64, 1, 2), 256, 0, stream>>>(W2, 64, BN);
  edge_epi64<<<dim3(BN / 4, 1), 256, 0, stream>>>(s2, t2, 64, 1, 1, BN, N);
  // ---- layer 3: (C=64) -> cols 128:256, 2 chunks; next layer CPAD=128
  knn_fused<64><<<dim3(N / 64, B, NPART), 256, 0, stream>>>(N);
  gmat_mfma<64><<<dim3(BN / 64, 2, 2), 256, 0, stream>>>(W3, 64, BN);
  zero_norms<<<BN / 256, 256, 0, stream>>>();
  edge_epi64<<<dim3(BN / 4, 2), 256, 0, stream>>>(s3, t3, 128, 2, 2, BN, N);
  // ---- layer 4: (C=128) -> cols 256:512, 4 chunks; no next knn
  knn_fused<128><<<dim3(N / 64, B, NPART), 256, 0, stream>>>(N);
  gmat_mfma<128><<<dim3(BN / 64, 4, 2), 256, 0, stream>>>(W4, 128, BN);
  edge_epi64<<<dim3(BN / 4, 4), 256, 0, stream>>>(s4, t4, 256, -1, 0, BN, N);
  // ---- W5 + global max pool
  w5max_mfma<<<dim3(8, 16, 8), 256, 0, stream>>>(s5, t5, N);
  poolred_kernel<<<32, 256, 0, stream>>>();
  // ---- FC head
  fc_kernel<<<(8 * 512 * 64) / 256, 256, 0, stream>>>(OFF_POOLED, Wf1, nullptr, sf1, tf1, OFF_H1, 1, nullptr, 8, 1024, 512, 1);
  fc_kernel<<<(8 * 256 * 64) / 256, 256, 0, stream>>>(OFF_H1, Wf2, bf2, sf2, tf2, OFF_H2, 1, nullptr, 8, 512, 256, 1);
  fc_kernel<<<6, 256, 0, stream>>>(OFF_H2, Wf3, bf3, nullptr, nullptr, 0, 0, d_out, 8, 256, 3, 0);
}

// Round 18
// 581.299 us; speedup vs baseline: 1.1909x; 1.0280x over previous
//
#include <hip/hip_runtime.h>
#include <hip/hip_bf16.h>

// DGCNN-style KNN classifier. B=8, N=2048, K=10.
// g_flag=1 -> bf16 inputs, 0 -> fp32 (runtime probe). Output same dtype.
// Scratch in static __device__ globals; every byte read is written earlier in
// the same launch (graph-replay safe; layer-3 norms re-zeroed before atomics).
//
// R17->R18: W1..W4 pre-split ONCE into global frag-tiled g_wfh/g_wfl (like
// W5): gmat_mfma loses per-block LDS staging (identical across blockIdx.x —
// redundant ~500 VALU/thread) + its barrier; B-frags now L2-resident loads.

#define NEG 0.2f
#define FMAX 3.402823466e+38f
#define KINIT 0x7F7FFFFFFFFFFFFFull  // (FLT_MAX bits << 32) | 0xFFFFFFFF

typedef __hip_bfloat16 bf16;
typedef __attribute__((ext_vector_type(8))) short s8v;    // 8 bf16
typedef __attribute__((ext_vector_type(4))) float f32x4;  // MFMA acc
typedef unsigned long long u64;

#define BB 8
#define NN 2048
#define BNTOT (BB * NN)
#define NPART 4

#define OFF_NORMS ((size_t)0)
#define OFF_PART (OFF_NORMS + BNTOT)
#define OFF_POOLED (OFF_PART + 8 * 1024 * 32)
#define OFF_H1 (OFF_POOLED + 8 * 1024)
#define OFF_H2 (OFF_H1 + 8 * 512)
#define WSF_TOTAL (OFF_H2 + 8 * 256)

// frag-tiled W1..W4 halves: base[l] + z*half[l] + i
// L1: half 2048 | L2: 4096 | L3: 8192 | L4: 32768  (elems)
#define WB1 0
#define WB2 4096
#define WB3 12288
#define WB4 28672
#define WTOT 94208

__device__ float g_ws_f[WSF_TOTAL];
__device__ float g_G[(size_t)8 * BNTOT * 64];     // [chunk(<=4)][z(2)][BN][64]
__device__ u64 g_pk[(size_t)BNTOT * NPART * 10];  // partial top-10 packed keys
__device__ int g_flag;                            // 1 = bf16 inputs, 0 = fp32
__device__ unsigned short g_hi[(size_t)BNTOT * 512];    // knn/gmat split (frag-tiled)
__device__ unsigned short g_lo[(size_t)BNTOT * 512];
__device__ unsigned short g_xhi5[(size_t)BNTOT * 512];  // W5-layout activations
__device__ unsigned short g_xlo5[(size_t)BNTOT * 512];
__device__ unsigned short g_whi[1024 * 512];            // split W5 weights
__device__ unsigned short g_wlo[1024 * 512];
__device__ unsigned short g_wfh[WTOT];                  // split W1..W4 (frag-tiled)
__device__ unsigned short g_wfl[WTOT];

__device__ __forceinline__ float ldany(const void* p, size_t i, int isb) {
  if (isb) return __bfloat162float(((const bf16*)p)[i]);
  return ((const float*)p)[i];
}

// ---------------- dtype probe ----------------
__global__ void probe_kernel(const void* pts) {
  const unsigned* w = (const unsigned*)pts;
  int cnt = 0;
  for (int i = 0; i < 256; ++i) {
    unsigned e2 = (w[i] >> 7) & 0xFF;
    cnt += (e2 >= 110 && e2 <= 135);
  }
  g_flag = (cnt > 128) ? 1 : 0;
}

// ---------------- norms (layer-1 input only) ----------------
__global__ void norms_kernel(const void* xraw, int lda, int C, int BN) {
  const int isb = g_flag;
  float* norms = g_ws_f + OFF_NORMS;
  int row = blockIdx.x * (blockDim.x >> 6) + (threadIdx.x >> 6);
  int lane = threadIdx.x & 63;
  if (row >= BN) return;
  float s = 0.f;
  for (int c = lane; c < C; c += 64) {
    float v = ldany(xraw, (size_t)row * lda + c, isb);
    s += v * v;
  }
#pragma unroll
  for (int off = 32; off > 0; off >>= 1) s += __shfl_down(s, off, 64);
  if (lane == 0) norms[row] = s;
}

__global__ void zero_norms() {
  int i = blockIdx.x * blockDim.x + threadIdx.x;
  if (i < BNTOT) g_ws_f[OFF_NORMS + i] = 0.f;
}

// ------- split-bf16 into MFMA-fragment-tile layout (points + W5 weights) -------
__global__ void split_kernel(const void* xraw, int lda, int C,
                             int csh2, int dst, int total) {
  int i = blockIdx.x * blockDim.x + threadIdx.x;
  if (i >= total) return;
  const int isb = g_flag;
  int t = i >> 9, win = i & 511;
  int quad = win >> 7, l16 = (win >> 3) & 15, j = win & 7;
  int ktiles_m1 = (1 << csh2) - 1;
  int rg = t >> csh2, kt = t & ktiles_m1;
  int r = rg * 16 + l16;
  int c = kt * 32 + quad * 8 + j;
  float v = (c < C) ? ldany(xraw, (size_t)r * lda + c, isb) : 0.f;
  bf16 h = __float2bfloat16(v);
  float hf = __bfloat162float(h);
  bf16 l = __float2bfloat16(v - hf);
  unsigned short* H = dst ? g_whi : g_hi;
  unsigned short* L = dst ? g_wlo : g_lo;
  H[i] = *(unsigned short*)&h;
  L[i] = *(unsigned short*)&l;
}

// ------- split W-halves (W1..W4) into frag-tiled g_wfh/g_wfl; z = blockIdx.y -------
__global__ void split_w(const void* W, int C, int ktsh, int wbase, int whalf,
                        int total) {
  int i = blockIdx.x * blockDim.x + threadIdx.x;  // index within one z-half
  if (i >= total) return;
  int z = blockIdx.y;
  const int isb = g_flag;
  int t = i >> 9, win = i & 511;
  int quad = win >> 7, l16 = (win >> 3) & 15, j = win & 7;
  int rg = t >> ktsh, kt = t & ((1 << ktsh) - 1);
  int orow = rg * 16 + l16;
  int c = kt * 32 + quad * 8 + j;
  float v = (c < C) ? ldany(W, (size_t)orow * (2 * C) + (size_t)z * C + c, isb) : 0.f;
  bf16 h = __float2bfloat16(v);
  float hf = __bfloat162float(h);
  bf16 l = __float2bfloat16(v - hf);
  g_wfh[wbase + z * whalf + i] = *(unsigned short*)&h;
  g_wfl[wbase + z * whalf + i] = *(unsigned short*)&l;
}

// ------- fused KNN (partitioned): MFMA distances + per-partition top-10 -------
// Double-buffered sd: one barrier per tile.
template <int CPAD>
__global__ __launch_bounds__(256) void knn_fused(int N) {
  constexpr int KT = CPAD >> 5;
  __shared__ __align__(16) float sdbuf[2][64 * 68];  // 34816 B
  __shared__ float th[256];                          // [wave][query]
  const int tid = threadIdx.x;
  const int wave = tid >> 6, lane = tid & 63;
  const int quad = lane >> 4, l16 = lane & 15;
  const int b = blockIdx.y;
  const int q0 = blockIdx.x * 64;
  const int part = blockIdx.z;
  const int PN = N / NPART;
  const size_t rowb = (size_t)b * N;
  const float* norms = g_ws_f + OFF_NORMS;

  const int arg = (int)((rowb + q0) >> 4) + wave;
  s8v ah[KT], al[KT];
#pragma unroll
  for (int kt = 0; kt < KT; ++kt) {
    const size_t abase = ((size_t)arg * KT + kt) * 512 + lane * 8;
    ah[kt] = *(const s8v*)(g_hi + abase);
    al[kt] = *(const s8v*)(g_lo + abase);
  }

  const int selfn = q0 + lane;  // this thread maintains query q0+lane
  const float qn = norms[rowb + selfn];
  u64 K[10];
#pragma unroll
  for (int i = 0; i < 10; ++i) K[i] = KINIT;
  th[wave * 64 + lane] = FMAX;  // visible after first in-loop barrier

  int pb = 0;
  for (int m0 = part * PN; m0 < (part + 1) * PN; m0 += 64, pb ^= 1) {
    f32x4 acc[4];
#pragma unroll
    for (int s = 0; s < 4; ++s) acc[s] = (f32x4){0.f, 0.f, 0.f, 0.f};
    const int brg0 = (int)((rowb + m0) >> 4);
#pragma unroll
    for (int kt = 0; kt < KT; ++kt) {
#pragma unroll
      for (int s = 0; s < 4; ++s) {
        const size_t bbase = ((size_t)(brg0 + s) * KT + kt) * 512 + lane * 8;
        s8v bh = *(const s8v*)(g_hi + bbase);
        s8v bl = *(const s8v*)(g_lo + bbase);
        acc[s] = __builtin_amdgcn_mfma_f32_16x16x32_bf16(ah[kt], bh, acc[s], 0, 0, 0);
        acc[s] = __builtin_amdgcn_mfma_f32_16x16x32_bf16(ah[kt], bl, acc[s], 0, 0, 0);
        acc[s] = __builtin_amdgcn_mfma_f32_16x16x32_bf16(al[kt], bh, acc[s], 0, 0, 0);
      }
    }
    float* sd = sdbuf[pb];
#pragma unroll
    for (int s = 0; s < 4; ++s) {
      int ml = s * 16 + l16;
      float nm = norms[rowb + m0 + ml];
#pragma unroll
      for (int r = 0; r < 4; ++r)
        sd[(wave * 16 + quad * 4 + r) * 68 + ml] = nm - 2.f * acc[s][r];
    }
    __syncthreads();  // single barrier per tile
    const float T = fminf(fminf(th[lane], th[64 + lane]),
                          fminf(th[128 + lane], th[192 + lane]));
    const int mbase = m0 + wave * 16;
    const float* srow = sd + lane * 68 + wave * 16;
    unsigned pass = 0;
#pragma unroll
    for (int jj = 0; jj < 16; jj += 4) {
      float4 d4 = *(const float4*)(srow + jj);
      pass |= (unsigned)(d4.x + qn <= T) << jj;
      pass |= (unsigned)(d4.y + qn <= T) << (jj + 1);
      pass |= (unsigned)(d4.z + qn <= T) << (jj + 2);
      pass |= (unsigned)(d4.w + qn <= T) << (jj + 3);
    }
    if ((unsigned)(selfn - mbase) < 16u) pass &= ~(1u << (selfn - mbase));
    while (pass) {
      int jj = __builtin_ctz(pass);
      pass &= pass - 1;
      int m = mbase + jj;
      float d = fmaxf(srow[jj] + qn, 0.f);
      u64 key = ((u64)__float_as_uint(d) << 32) | (unsigned)m;
      if (key < K[9]) {
        bool prev = true;
#pragma unroll
        for (int s2 = 9; s2 >= 1; --s2) {
          bool sh = key < K[s2 - 1];
          K[s2] = sh ? K[s2 - 1] : (prev ? key : K[s2]);
          prev = sh;
        }
        if (prev) K[0] = key;
      }
    }
    th[wave * 64 + lane] = __uint_as_float((unsigned)(K[9] >> 32));
  }
  __syncthreads();  // sd/th dead; reuse sdbuf for merge lists
  u64* mlist = (u64*)sdbuf;
#pragma unroll
  for (int i = 0; i < 10; ++i) mlist[(lane * 4 + wave) * 10 + i] = K[i];
  __syncthreads();
  if (tid < 64) {
    int q = tid;
    int p0 = 0, p1 = 0, p2 = 0, p3 = 0;
    size_t ob = ((rowb + q0 + q) * NPART + part) * 10;
    for (int cnt = 0; cnt < 10; ++cnt) {
      u64 k0 = mlist[(q * 4 + 0) * 10 + p0];
      u64 k1 = mlist[(q * 4 + 1) * 10 + p1];
      u64 k2 = mlist[(q * 4 + 2) * 10 + p2];
      u64 k3 = mlist[(q * 4 + 3) * 10 + p3];
      u64 bk = k0; int bp = 0;
      if (k1 < bk) { bk = k1; bp = 1; }
      if (k2 < bk) { bk = k2; bp = 2; }
      if (k3 < bk) { bk = k3; bp = 3; }
      if (bp == 0) ++p0; else if (bp == 1) ++p1; else if (bp == 2) ++p2; else ++p3;
      g_pk[ob + cnt] = bk;
    }
  }
}

// --- G[chunk][z] = X @ W_half^T via MFMA; A from g_hi/g_lo, B from g_wfh/g_wfl ---
template <int CPAD>
__global__ __launch_bounds__(256) void gmat_mfma(int wbase, int whalf, int BN) {
  constexpr int KT = CPAD >> 5;
  const int tid = threadIdx.x;
  const int wave = tid >> 6, lane = tid & 63;
  const int quad = lane >> 4, l16 = lane & 15;
  const int r0 = blockIdx.x * 64;
  const int chunk = blockIdx.y;
  const int z = blockIdx.z;
  const int wz = wbase + z * whalf;
  const int wrg0 = chunk * 4;  // row-group base within this layer's W half
  f32x4 acc[4];
#pragma unroll
  for (int s = 0; s < 4; ++s) acc[s] = (f32x4){0.f, 0.f, 0.f, 0.f};
  const int arg = (r0 >> 4) + wave;
#pragma unroll
  for (int kt = 0; kt < KT; ++kt) {
    const size_t abase = ((size_t)arg * KT + kt) * 512 + lane * 8;
    s8v ah = *(const s8v*)(g_hi + abase);
    s8v al = *(const s8v*)(g_lo + abase);
#pragma unroll
    for (int s = 0; s < 4; ++s) {
      const size_t woff = (size_t)wz + ((size_t)(wrg0 + s) * KT + kt) * 512 + lane * 8;
      s8v bh = *(const s8v*)(g_wfh + woff);
      s8v bl = *(const s8v*)(g_wfl + woff);
      acc[s] = __builtin_amdgcn_mfma_f32_16x16x32_bf16(ah, bh, acc[s], 0, 0, 0);
      acc[s] = __builtin_amdgcn_mfma_f32_16x16x32_bf16(ah, bl, acc[s], 0, 0, 0);
      acc[s] = __builtin_amdgcn_mfma_f32_16x16x32_bf16(al, bh, acc[s], 0, 0, 0);
    }
  }
  float* Gz = g_G + (size_t)(chunk * 2 + z) * BN * 64;
#pragma unroll
  for (int s = 0; s < 4; ++s)
#pragma unroll
    for (int r = 0; r < 4; ++r)
      Gz[(size_t)(r0 + wave * 16 + quad * 4 + r) * 64 + s * 16 + l16] = acc[s][r];
}

// ------- edge-conv epilogue: inline NPART-merge (rank-select) + gather+max
//         + fused splits + norms. One wave per row; wave-internal LDS only.
__global__ void edge_epi64(const void* s, const void* t, int colbase,
                           int knn_csh2, int norms_mode, int BN, int N) {
  __shared__ u64 kbuf[4][40];
  __shared__ int oidx[4][10];
  const int isb = g_flag;
  int tid = threadIdx.x;
  int p = tid >> 6, o = tid & 63;  // p = wave = row-in-block
  int row = blockIdx.x * 4 + p;
  int chunk = blockIdx.y;
  const float* G1 = g_G + (size_t)(chunk * 2 + 0) * BN * 64;
  const float* G2 = g_G + (size_t)(chunk * 2 + 1) * BN * 64;
  int b = row / N;
  if (o < 40) kbuf[p][o] = g_pk[(size_t)row * 40 + o];
  if (o < 40) {
    u64 myk = kbuf[p][o];
    int rank = 0;
#pragma unroll 8
    for (int j = 0; j < 40; ++j) rank += (kbuf[p][j] < myk);
    if (rank < 10) oidx[p][rank] = (int)(myk & 0xFFFFFFFFu);
  }
  float g1n = G1[(size_t)row * 64 + o];
  float base = G2[(size_t)row * 64 + o] - g1n;
  int co = chunk * 64 + o;
  float sv = ldany(s, co, isb), tv = ldany(t, co, isb);
  float mx = -FMAX;
#pragma unroll
  for (int k = 0; k < 10; ++k) {
    int m = oidx[p][k];
    m = (m < 0) ? 0 : ((m >= N) ? N - 1 : m);
    float h = sv * (G1[((size_t)b * N + m) * 64 + o] + base) + tv;
    h = (h >= 0.f) ? h : NEG * h;
    mx = fmaxf(mx, h);
  }
  bf16 h16 = __float2bfloat16(mx);
  float hf = __bfloat162float(h16);
  bf16 l16v = __float2bfloat16(mx - hf);
  unsigned short hu = *(unsigned short*)&h16;
  unsigned short lu = *(unsigned short*)&l16v;
  if (knn_csh2 >= 0) {
    int KTL = 1 << knn_csh2;
    size_t ki = ((size_t)(row >> 4) * KTL + (co >> 5)) * 512 +
                ((size_t)((co >> 3) & 3)) * 128 + (row & 15) * 8 + (co & 7);
    g_hi[ki] = hu; g_lo[ki] = lu;
  }
  {
    int gc = colbase + co;
    size_t wi = ((size_t)(row >> 4) * 16 + (gc >> 5)) * 512 +
                ((size_t)((gc >> 3) & 3)) * 128 + (row & 15) * 8 + (gc & 7);
    g_xhi5[wi] = hu; g_xlo5[wi] = lu;
  }
  if (norms_mode) {
    float ns = mx * mx;
#pragma unroll
    for (int off = 32; off > 0; off >>= 1) ns += __shfl_down(ns, off, 64);
    if (o == 0) {
      if (norms_mode == 1) g_ws_f[OFF_NORMS + row] = ns;
      else atomicAdd(&g_ws_f[OFF_NORMS + row], ns);
    }
  }
}

// ------- W5 MFMA + max over n; wave tile 64n x 64o (s5>0: affine after max) ----
__global__ __launch_bounds__(256) void w5max_mfma(const void* s5, const void* t5, int N) {
  const int tid = threadIdx.x;
  const int wave = tid >> 6, lane = tid & 63;
  const int quad = lane >> 4, l16 = lane & 15;
  const int b = blockIdx.z;
  const int o0 = blockIdx.y * 64, n0 = blockIdx.x * 256;
  f32x4 acc[4][4];
#pragma unroll
  for (int a = 0; a < 4; ++a)
#pragma unroll
    for (int s = 0; s < 4; ++s) acc[a][s] = (f32x4){0.f, 0.f, 0.f, 0.f};

  const int arg0 = (int)(((size_t)b * N + n0) >> 4) + wave * 4;
  const int wrg0 = o0 >> 4;
  for (int kt = 0; kt < 16; ++kt) {
    s8v ah[4], al[4];
#pragma unroll
    for (int a = 0; a < 4; ++a) {
      const size_t abase = ((size_t)(arg0 + a) * 16 + kt) * 512 + lane * 8;
      ah[a] = *(const s8v*)(g_xhi5 + abase);
      al[a] = *(const s8v*)(g_xlo5 + abase);
    }
#pragma unroll
    for (int s = 0; s < 4; ++s) {
      const size_t bbase = ((size_t)(wrg0 + s) * 16 + kt) * 512 + lane * 8;
      s8v bh = *(const s8v*)(g_whi + bbase);
      s8v bl = *(const s8v*)(g_wlo + bbase);
#pragma unroll
      for (int a = 0; a < 4; ++a) {
        acc[a][s] = __builtin_amdgcn_mfma_f32_16x16x32_bf16(ah[a], bh, acc[a][s], 0, 0, 0);
        acc[a][s] = __builtin_amdgcn_mfma_f32_16x16x32_bf16(ah[a], bl, acc[a][s], 0, 0, 0);
        acc[a][s] = __builtin_amdgcn_mfma_f32_16x16x32_bf16(al[a], bh, acc[a][s], 0, 0, 0);
      }
    }
  }
  __shared__ float red[4][64];
  const int isb = g_flag;
#pragma unroll
  for (int s = 0; s < 4; ++s) {
    float m4 = -FMAX;
#pragma unroll
    for (int a = 0; a < 4; ++a)
#pragma unroll
      for (int r = 0; r < 4; ++r) m4 = fmaxf(m4, acc[a][s][r]);
#pragma unroll
    for (int off = 16; off < 64; off <<= 1) m4 = fmaxf(m4, __shfl_down(m4, off, 64));
    if (quad == 0) red[wave][s * 16 + l16] = m4;
  }
  __syncthreads();
  if (tid < 64) {
    float m = fmaxf(fmaxf(red[0][tid], red[1][tid]), fmaxf(red[2][tid], red[3][tid]));
    int o = o0 + tid;
    float sv = ldany(s5, o, isb), tv = ldany(t5, o, isb);
    float h = sv * m + tv;
    h = (h >= 0.f) ? h : NEG * h;
    g_ws_f[OFF_PART + ((size_t)b * 1024 + o) * 8 + blockIdx.x] = h;
  }
}

__global__ void poolred_kernel() {
  const float* part = g_ws_f + OFF_PART;
  float* pooled = g_ws_f + OFF_POOLED;
  int i = blockIdx.x * blockDim.x + threadIdx.x;
  if (i >= 8 * 1024) return;
  const float* p = part + (size_t)i * 8;
  float m = -FMAX;
#pragma unroll
  for (int j = 0; j < 8; ++j) m = fmaxf(m, p[j]);
  pooled[i] = m;
}

// ---------------- FC: one wave per output ----------------
__global__ void fc_kernel(size_t inoff, const void* W, const void* bias,
                          const void* s, const void* t, size_t outoff, int has_out,
                          void* OUTB, int Bb, int IC, int OC, int act) {
  const int isb = g_flag;
  const float* IN = g_ws_f + inoff;
  int gw = (blockIdx.x * blockDim.x + threadIdx.x) >> 6;
  int lane = threadIdx.x & 63;
  if (gw >= Bb * OC) return;
  int b = gw / OC, o = gw % OC;
  const float* in = IN + (size_t)b * IC;
  float acc = 0.f;
  for (int c = lane; c < IC; c += 64) acc += in[c] * ldany(W, (size_t)o * IC + c, isb);
#pragma unroll
  for (int off = 32; off > 0; off >>= 1) acc += __shfl_down(acc, off, 64);
  if (lane == 0) {
    float h = acc;
    if (bias) h += ldany(bias, o, isb);
    if (s) h = h * ldany(s, o, isb) + ldany(t, o, isb);
    if (act) h = (h >= 0.f) ? h : NEG * h;
    if (has_out) g_ws_f[outoff + (size_t)b * OC + o] = h;
    if (OUTB) {
      if (isb) ((bf16*)OUTB)[(size_t)b * OC + o] = __float2bfloat16(h);
      else ((float*)OUTB)[(size_t)b * OC + o] = h;
    }
  }
}

extern "C" void kernel_launch(void* const* d_in, const int* in_sizes, int n_in,
                              void* d_out, int out_size, void* d_ws, size_t ws_size,
                              hipStream_t stream) {
  const int B = 8, N = 2048, BN = B * N;
  const void* points = d_in[0];
  const void *W1 = d_in[1], *s1 = d_in[2], *t1 = d_in[3];
  const void *W2 = d_in[4], *s2 = d_in[5], *t2 = d_in[6];
  const void *W3 = d_in[7], *s3 = d_in[8], *t3 = d_in[9];
  const void *W4 = d_in[10], *s4 = d_in[11], *t4 = d_in[12];
  const void *W5 = d_in[13], *s5 = d_in[14], *t5 = d_in[15];
  const void *Wf1 = d_in[16], *sf1 = d_in[17], *tf1 = d_in[18];
  const void *Wf2 = d_in[19], *bf2 = d_in[20], *sf2 = d_in[21], *tf2 = d_in[22];
  const void *Wf3 = d_in[23], *bf3 = d_in[24];

  probe_kernel<<<1, 1, 0, stream>>>(points);
  split_kernel<<<(1024 * 512) / 256, 256, 0, stream>>>(W5, 512, 512, 4, 1, 1024 * 512);
  // pre-split W1..W4 halves into frag-tiled g_wfh/g_wfl (once)
  split_w<<<dim3(2048 / 256, 2), 256, 0, stream>>>(W1, 3, 0, WB1, 2048, 2048);
  split_w<<<dim3(4096 / 256, 2), 256, 0, stream>>>(W2, 64, 1, WB2, 4096, 4096);
  split_w<<<dim3(8192 / 256, 2), 256, 0, stream>>>(W3, 64, 1, WB3, 8192, 8192);
  split_w<<<dim3(32768 / 256, 2), 256, 0, stream>>>(W4, 128, 2, WB4, 32768, 32768);

  // ---- layer 1: points (C=3, CPAD=32) -> cols 0:64
  norms_kernel<<<BN / 4, 256, 0, stream>>>(points, 3, 3, BN);
  split_kernel<<<(BN * 32) / 256, 256, 0, stream>>>(points, 3, 3, 0, 0, BN * 32);
  knn_fused<32><<<dim3(N / 64, B, NPART), 256, 0, stream>>>(N);
  gmat_mfma<32><<<dim3(BN / 64, 1, 2), 256, 0, stream>>>(WB1, 2048, BN);
  edge_epi64<<<dim3(BN / 4, 1), 256, 0, stream>>>(s1, t1, 0, 1, 1, BN, N);
  // ---- layer 2: (C=64, CPAD=64) -> cols 64:128
  knn_fused<64><<<dim3(N / 64, B, NPART), 256, 0, stream>>>(N);
  gmat_mfma<64><<<dim3(BN / 64, 1, 2), 256, 0, stream>>>(WB2, 4096, BN);
  edge_epi64<<<dim3(BN / 4, 1), 256, 0, stream>>>(s2, t2, 64, 1, 1, BN, N);
  // ---- layer 3: (C=64) -> cols 128:256, 2 chunks; next layer CPAD=128
  knn_fused<64><<<dim3(N / 64, B, NPART), 256, 0, stream>>>(N);
  gmat_mfma<64><<<dim3(BN / 64, 2, 2), 256, 0, stream>>>(WB3, 8192, BN);
  zero_norms<<<BN / 256, 256, 0, stream>>>();
  edge_epi64<<<dim3(BN / 4, 2), 256, 0, stream>>>(s3, t3, 128, 2, 2, BN, N);
  // ---- layer 4: (C=128) -> cols 256:512, 4 chunks; no next knn
  knn_fused<128><<<dim3(N / 64, B, NPART), 256, 0, stream>>>(N);
  gmat_mfma<128><<<dim3(BN / 64, 4, 2), 256, 0, stream>>>(WB4, 32768, BN);
  edge_epi64<<<dim3(BN / 4, 4), 256, 0, stream>>>(s4, t4, 256, -1, 0, BN, N);
  // ---- W5 + global max pool
  w5max_mfma<<<dim3(8, 16, 8), 256, 0, stream>>>(s5, t5, N);
  poolred_kernel<<<32, 256, 0, stream>>>();
  // ---- FC head
  fc_kernel<<<(8 * 512 * 64) / 256, 256, 0, stream>>>(OFF_POOLED, Wf1, nullptr, sf1, tf1, OFF_H1, 1, nullptr, 8, 1024, 512, 1);
  fc_kernel<<<(8 * 256 * 64) / 256, 256, 0, stream>>>(OFF_H1, Wf2, bf2, sf2, tf2, OFF_H2, 1, nullptr, 8, 512, 256, 1);
  fc_kernel<<<6, 256, 0, stream>>>(OFF_H2, Wf3, bf3, nullptr, nullptr, 0, 0, d_out, 8, 256, 3, 0);
}

// Round 19
// 571.067 us; speedup vs baseline: 1.2122x; 1.0179x over previous
//
#include <hip/hip_runtime.h>
#include <hip/hip_bf16.h>

// DGCNN-style KNN classifier. B=8, N=2048, K=10.
// g_flag=1 -> bf16 inputs, 0 -> fp32 (runtime probe). Output same dtype.
// Scratch in static __device__ globals; every byte read is written earlier in
// the same launch (graph-replay safe; norms/g_th re-initialized each launch).
//
// R18->R19: device-global per-query threshold g_th (u32 = fp32 bits of the
// 10th-best distance; d>=0 so uint order == float order), maintained via
// atomicMin by all 16 lists (4 waves x 4 partitions) of each query. Phase-1
// filters vs this grid-wide bound -> warm-up paid once, not x16. Exact: any
// list's K[9] >= global 10th-best key; ties pass; every true top-10 key
// strictly beats K[9] when scanned. Block-level th LDS removed (subsumed).

#define NEG 0.2f
#define FMAX 3.402823466e+38f
#define FMAXB 0x7F7FFFFFu
#define KINIT 0x7F7FFFFFFFFFFFFFull  // (FLT_MAX bits << 32) | 0xFFFFFFFF

typedef __hip_bfloat16 bf16;
typedef __attribute__((ext_vector_type(8))) short s8v;    // 8 bf16
typedef __attribute__((ext_vector_type(4))) float f32x4;  // MFMA acc
typedef unsigned long long u64;

#define BB 8
#define NN 2048
#define BNTOT (BB * NN)
#define NPART 4

#define OFF_NORMS ((size_t)0)
#define OFF_PART (OFF_NORMS + BNTOT)
#define OFF_POOLED (OFF_PART + 8 * 1024 * 32)
#define OFF_H1 (OFF_POOLED + 8 * 1024)
#define OFF_H2 (OFF_H1 + 8 * 512)
#define WSF_TOTAL (OFF_H2 + 8 * 256)

// frag-tiled W1..W4 halves: base[l] + z*half[l] + i
#define WB1 0
#define WB2 4096
#define WB3 12288
#define WB4 28672
#define WTOT 94208

__device__ float g_ws_f[WSF_TOTAL];
__device__ float g_G[(size_t)8 * BNTOT * 64];     // [chunk(<=4)][z(2)][BN][64]
__device__ u64 g_pk[(size_t)BNTOT * NPART * 10];  // partial top-10 packed keys
__device__ unsigned g_th[BNTOT];                  // per-query dist bound (fp32 bits)
__device__ int g_flag;                            // 1 = bf16 inputs, 0 = fp32
__device__ unsigned short g_hi[(size_t)BNTOT * 512];    // knn/gmat split (frag-tiled)
__device__ unsigned short g_lo[(size_t)BNTOT * 512];
__device__ unsigned short g_xhi5[(size_t)BNTOT * 512];  // W5-layout activations
__device__ unsigned short g_xlo5[(size_t)BNTOT * 512];
__device__ unsigned short g_whi[1024 * 512];            // split W5 weights
__device__ unsigned short g_wlo[1024 * 512];
__device__ unsigned short g_wfh[WTOT];                  // split W1..W4 (frag-tiled)
__device__ unsigned short g_wfl[WTOT];

__device__ __forceinline__ float ldany(const void* p, size_t i, int isb) {
  if (isb) return __bfloat162float(((const bf16*)p)[i]);
  return ((const float*)p)[i];
}

// ---------------- dtype probe ----------------
__global__ void probe_kernel(const void* pts) {
  const unsigned* w = (const unsigned*)pts;
  int cnt = 0;
  for (int i = 0; i < 256; ++i) {
    unsigned e2 = (w[i] >> 7) & 0xFF;
    cnt += (e2 >= 110 && e2 <= 135);
  }
  g_flag = (cnt > 128) ? 1 : 0;
}

// ---------------- norms (layer-1 input only) + g_th init ----------------
__global__ void norms_kernel(const void* xraw, int lda, int C, int BN) {
  const int isb = g_flag;
  float* norms = g_ws_f + OFF_NORMS;
  int row = blockIdx.x * (blockDim.x >> 6) + (threadIdx.x >> 6);
  int lane = threadIdx.x & 63;
  if (row >= BN) return;
  float s = 0.f;
  for (int c = lane; c < C; c += 64) {
    float v = ldany(xraw, (size_t)row * lda + c, isb);
    s += v * v;
  }
#pragma unroll
  for (int off = 32; off > 0; off >>= 1) s += __shfl_down(s, off, 64);
  if (lane == 0) { norms[row] = s; g_th[row] = FMAXB; }
}

__global__ void zero_norms() {
  int i = blockIdx.x * blockDim.x + threadIdx.x;
  if (i < BNTOT) g_ws_f[OFF_NORMS + i] = 0.f;
}

// ------- split-bf16 into MFMA-fragment-tile layout (points + W5 weights) -------
__global__ void split_kernel(const void* xraw, int lda, int C,
                             int csh2, int dst, int total) {
  int i = blockIdx.x * blockDim.x + threadIdx.x;
  if (i >= total) return;
  const int isb = g_flag;
  int t = i >> 9, win = i & 511;
  int quad = win >> 7, l16 = (win >> 3) & 15, j = win & 7;
  int ktiles_m1 = (1 << csh2) - 1;
  int rg = t >> csh2, kt = t & ktiles_m1;
  int r = rg * 16 + l16;
  int c = kt * 32 + quad * 8 + j;
  float v = (c < C) ? ldany(xraw, (size_t)r * lda + c, isb) : 0.f;
  bf16 h = __float2bfloat16(v);
  float hf = __bfloat162float(h);
  bf16 l = __float2bfloat16(v - hf);
  unsigned short* H = dst ? g_whi : g_hi;
  unsigned short* L = dst ? g_wlo : g_lo;
  H[i] = *(unsigned short*)&h;
  L[i] = *(unsigned short*)&l;
}

// ------- split W-halves (W1..W4) into frag-tiled g_wfh/g_wfl; z = blockIdx.y -------
__global__ void split_w(const void* W, int C, int ktsh, int wbase, int whalf,
                        int total) {
  int i = blockIdx.x * blockDim.x + threadIdx.x;
  if (i >= total) return;
  int z = blockIdx.y;
  const int isb = g_flag;
  int t = i >> 9, win = i & 511;
  int quad = win >> 7, l16 = (win >> 3) & 15, j = win & 7;
  int rg = t >> ktsh, kt = t & ((1 << ktsh) - 1);
  int orow = rg * 16 + l16;
  int c = kt * 32 + quad * 8 + j;
  float v = (c < C) ? ldany(W, (size_t)orow * (2 * C) + (size_t)z * C + c, isb) : 0.f;
  bf16 h = __float2bfloat16(v);
  float hf = __bfloat162float(h);
  bf16 l = __float2bfloat16(v - hf);
  g_wfh[wbase + z * whalf + i] = *(unsigned short*)&h;
  g_wfl[wbase + z * whalf + i] = *(unsigned short*)&l;
}

// ------- fused KNN (partitioned): MFMA distances + per-partition top-10 -------
// Double-buffered sd (one barrier/tile); grid-global threshold via g_th.
template <int CPAD>
__global__ __launch_bounds__(256) void knn_fused(int N) {
  constexpr int KT = CPAD >> 5;
  __shared__ __align__(16) float sdbuf[2][64 * 68];  // 34816 B
  const int tid = threadIdx.x;
  const int wave = tid >> 6, lane = tid & 63;
  const int quad = lane >> 4, l16 = lane & 15;
  const int b = blockIdx.y;
  const int q0 = blockIdx.x * 64;
  const int part = blockIdx.z;
  const int PN = N / NPART;
  const size_t rowb = (size_t)b * N;
  const float* norms = g_ws_f + OFF_NORMS;

  const int arg = (int)((rowb + q0) >> 4) + wave;
  s8v ah[KT], al[KT];
#pragma unroll
  for (int kt = 0; kt < KT; ++kt) {
    const size_t abase = ((size_t)arg * KT + kt) * 512 + lane * 8;
    ah[kt] = *(const s8v*)(g_hi + abase);
    al[kt] = *(const s8v*)(g_lo + abase);
  }

  const int selfn = q0 + lane;  // this thread maintains query q0+lane
  const float qn = norms[rowb + selfn];
  u64 K[10];
#pragma unroll
  for (int i = 0; i < 10; ++i) K[i] = KINIT;
  unsigned gth = FMAXB;  // cached grid-wide bound (fp32 bits)

  int pb = 0;
  for (int m0 = part * PN; m0 < (part + 1) * PN; m0 += 64, pb ^= 1) {
    f32x4 acc[4];
#pragma unroll
    for (int s = 0; s < 4; ++s) acc[s] = (f32x4){0.f, 0.f, 0.f, 0.f};
    const int brg0 = (int)((rowb + m0) >> 4);
#pragma unroll
    for (int kt = 0; kt < KT; ++kt) {
#pragma unroll
      for (int s = 0; s < 4; ++s) {
        const size_t bbase = ((size_t)(brg0 + s) * KT + kt) * 512 + lane * 8;
        s8v bh = *(const s8v*)(g_hi + bbase);
        s8v bl = *(const s8v*)(g_lo + bbase);
        acc[s] = __builtin_amdgcn_mfma_f32_16x16x32_bf16(ah[kt], bh, acc[s], 0, 0, 0);
        acc[s] = __builtin_amdgcn_mfma_f32_16x16x32_bf16(ah[kt], bl, acc[s], 0, 0, 0);
        acc[s] = __builtin_amdgcn_mfma_f32_16x16x32_bf16(al[kt], bh, acc[s], 0, 0, 0);
      }
    }
    float* sd = sdbuf[pb];
#pragma unroll
    for (int s = 0; s < 4; ++s) {
      int ml = s * 16 + l16;
      float nm = norms[rowb + m0 + ml];
#pragma unroll
      for (int r = 0; r < 4; ++r)
        sd[(wave * 16 + quad * 4 + r) * 68 + ml] = nm - 2.f * acc[s][r];
    }
    __syncthreads();  // single barrier per tile
    const float T = __uint_as_float(gth);
    const int mbase = m0 + wave * 16;
    const float* srow = sd + lane * 68 + wave * 16;
    unsigned pass = 0;
#pragma unroll
    for (int jj = 0; jj < 16; jj += 4) {
      float4 d4 = *(const float4*)(srow + jj);
      pass |= (unsigned)(d4.x + qn <= T) << jj;
      pass |= (unsigned)(d4.y + qn <= T) << (jj + 1);
      pass |= (unsigned)(d4.z + qn <= T) << (jj + 2);
      pass |= (unsigned)(d4.w + qn <= T) << (jj + 3);
    }
    if ((unsigned)(selfn - mbase) < 16u) pass &= ~(1u << (selfn - mbase));
    while (pass) {
      int jj = __builtin_ctz(pass);
      pass &= pass - 1;
      int m = mbase + jj;
      float d = fmaxf(srow[jj] + qn, 0.f);
      u64 key = ((u64)__float_as_uint(d) << 32) | (unsigned)m;
      if (key < K[9]) {
        bool prev = true;
#pragma unroll
        for (int s2 = 9; s2 >= 1; --s2) {
          bool sh = key < K[s2 - 1];
          K[s2] = sh ? K[s2 - 1] : (prev ? key : K[s2]);
          prev = sh;
        }
        if (prev) K[0] = key;
      }
    }
    // publish local bound; fold in grid-wide min (returned pre-op value)
    unsigned mine = (unsigned)(K[9] >> 32);
    unsigned old = atomicMin(&g_th[rowb + selfn], mine);
    gth = min(min(gth, old), mine);
  }
  __syncthreads();  // sd dead; reuse sdbuf for merge lists
  u64* mlist = (u64*)sdbuf;
#pragma unroll
  for (int i = 0; i < 10; ++i) mlist[(lane * 4 + wave) * 10 + i] = K[i];
  __syncthreads();
  if (tid < 64) {
    int q = tid;
    int p0 = 0, p1 = 0, p2 = 0, p3 = 0;
    size_t ob = ((rowb + q0 + q) * NPART + part) * 10;
    for (int cnt = 0; cnt < 10; ++cnt) {
      u64 k0 = mlist[(q * 4 + 0) * 10 + p0];
      u64 k1 = mlist[(q * 4 + 1) * 10 + p1];
      u64 k2 = mlist[(q * 4 + 2) * 10 + p2];
      u64 k3 = mlist[(q * 4 + 3) * 10 + p3];
      u64 bk = k0; int bp = 0;
      if (k1 < bk) { bk = k1; bp = 1; }
      if (k2 < bk) { bk = k2; bp = 2; }
      if (k3 < bk) { bk = k3; bp = 3; }
      if (bp == 0) ++p0; else if (bp == 1) ++p1; else if (bp == 2) ++p2; else ++p3;
      g_pk[ob + cnt] = bk;
    }
  }
}

// --- G[chunk][z] = X @ W_half^T via MFMA; A from g_hi/g_lo, B from g_wfh/g_wfl ---
template <int CPAD>
__global__ __launch_bounds__(256) void gmat_mfma(int wbase, int whalf, int BN) {
  constexpr int KT = CPAD >> 5;
  const int tid = threadIdx.x;
  const int wave = tid >> 6, lane = tid & 63;
  const int quad = lane >> 4, l16 = lane & 15;
  const int r0 = blockIdx.x * 64;
  const int chunk = blockIdx.y;
  const int z = blockIdx.z;
  const int wz = wbase + z * whalf;
  const int wrg0 = chunk * 4;
  f32x4 acc[4];
#pragma unroll
  for (int s = 0; s < 4; ++s) acc[s] = (f32x4){0.f, 0.f, 0.f, 0.f};
  const int arg = (r0 >> 4) + wave;
#pragma unroll
  for (int kt = 0; kt < KT; ++kt) {
    const size_t abase = ((size_t)arg * KT + kt) * 512 + lane * 8;
    s8v ah = *(const s8v*)(g_hi + abase);
    s8v al = *(const s8v*)(g_lo + abase);
#pragma unroll
    for (int s = 0; s < 4; ++s) {
      const size_t woff = (size_t)wz + ((size_t)(wrg0 + s) * KT + kt) * 512 + lane * 8;
      s8v bh = *(const s8v*)(g_wfh + woff);
      s8v bl = *(const s8v*)(g_wfl + woff);
      acc[s] = __builtin_amdgcn_mfma_f32_16x16x32_bf16(ah, bh, acc[s], 0, 0, 0);
      acc[s] = __builtin_amdgcn_mfma_f32_16x16x32_bf16(ah, bl, acc[s], 0, 0, 0);
      acc[s] = __builtin_amdgcn_mfma_f32_16x16x32_bf16(al, bh, acc[s], 0, 0, 0);
    }
  }
  float* Gz = g_G + (size_t)(chunk * 2 + z) * BN * 64;
#pragma unroll
  for (int s = 0; s < 4; ++s)
#pragma unroll
    for (int r = 0; r < 4; ++r)
      Gz[(size_t)(r0 + wave * 16 + quad * 4 + r) * 64 + s * 16 + l16] = acc[s][r];
}

// ------- edge-conv epilogue: inline NPART-merge (rank-select) + gather+max
//         + fused splits + norms + g_th re-init. One wave per row.
__global__ void edge_epi64(const void* s, const void* t, int colbase,
                           int knn_csh2, int norms_mode, int BN, int N) {
  __shared__ u64 kbuf[4][40];
  __shared__ int oidx[4][10];
  const int isb = g_flag;
  int tid = threadIdx.x;
  int p = tid >> 6, o = tid & 63;  // p = wave = row-in-block
  int row = blockIdx.x * 4 + p;
  int chunk = blockIdx.y;
  const float* G1 = g_G + (size_t)(chunk * 2 + 0) * BN * 64;
  const float* G2 = g_G + (size_t)(chunk * 2 + 1) * BN * 64;
  int b = row / N;
  if (o < 40) kbuf[p][o] = g_pk[(size_t)row * 40 + o];
  if (o < 40) {
    u64 myk = kbuf[p][o];
    int rank = 0;
#pragma unroll 8
    for (int j = 0; j < 40; ++j) rank += (kbuf[p][j] < myk);
    if (rank < 10) oidx[p][rank] = (int)(myk & 0xFFFFFFFFu);
  }
  float g1n = G1[(size_t)row * 64 + o];
  float base = G2[(size_t)row * 64 + o] - g1n;
  int co = chunk * 64 + o;
  float sv = ldany(s, co, isb), tv = ldany(t, co, isb);
  float mx = -FMAX;
#pragma unroll
  for (int k = 0; k < 10; ++k) {
    int m = oidx[p][k];
    m = (m < 0) ? 0 : ((m >= N) ? N - 1 : m);
    float h = sv * (G1[((size_t)b * N + m) * 64 + o] + base) + tv;
    h = (h >= 0.f) ? h : NEG * h;
    mx = fmaxf(mx, h);
  }
  bf16 h16 = __float2bfloat16(mx);
  float hf = __bfloat162float(h16);
  bf16 l16v = __float2bfloat16(mx - hf);
  unsigned short hu = *(unsigned short*)&h16;
  unsigned short lu = *(unsigned short*)&l16v;
  if (knn_csh2 >= 0) {
    int KTL = 1 << knn_csh2;
    size_t ki = ((size_t)(row >> 4) * KTL + (co >> 5)) * 512 +
                ((size_t)((co >> 3) & 3)) * 128 + (row & 15) * 8 + (co & 7);
    g_hi[ki] = hu; g_lo[ki] = lu;
  }
  {
    int gc = colbase + co;
    size_t wi = ((size_t)(row >> 4) * 16 + (gc >> 5)) * 512 +
                ((size_t)((gc >> 3) & 3)) * 128 + (row & 15) * 8 + (gc & 7);
    g_xhi5[wi] = hu; g_xlo5[wi] = lu;
  }
  if (norms_mode) {
    float ns = mx * mx;
#pragma unroll
    for (int off = 32; off > 0; off >>= 1) ns += __shfl_down(ns, off, 64);
    if (o == 0) {
      if (norms_mode == 1) g_ws_f[OFF_NORMS + row] = ns;
      else atomicAdd(&g_ws_f[OFF_NORMS + row], ns);
      g_th[row] = FMAXB;  // reset bound for next layer's knn
    }
  }
}

// ------- W5 MFMA + max over n; wave tile 64n x 64o (s5>0: affine after max) ----
__global__ __launch_bounds__(256) void w5max_mfma(const void* s5, const void* t5, int N) {
  const int tid = threadIdx.x;
  const int wave = tid >> 6, lane = tid & 63;
  const int quad = lane >> 4, l16 = lane & 15;
  const int b = blockIdx.z;
  const int o0 = blockIdx.y * 64, n0 = blockIdx.x * 256;
  f32x4 acc[4][4];
#pragma unroll
  for (int a = 0; a < 4; ++a)
#pragma unroll
    for (int s = 0; s < 4; ++s) acc[a][s] = (f32x4){0.f, 0.f, 0.f, 0.f};

  const int arg0 = (int)(((size_t)b * N + n0) >> 4) + wave * 4;
  const int wrg0 = o0 >> 4;
  for (int kt = 0; kt < 16; ++kt) {
    s8v ah[4], al[4];
#pragma unroll
    for (int a = 0; a < 4; ++a) {
      const size_t abase = ((size_t)(arg0 + a) * 16 + kt) * 512 + lane * 8;
      ah[a] = *(const s8v*)(g_xhi5 + abase);
      al[a] = *(const s8v*)(g_xlo5 + abase);
    }
#pragma unroll
    for (int s = 0; s < 4; ++s) {
      const size_t bbase = ((size_t)(wrg0 + s) * 16 + kt) * 512 + lane * 8;
      s8v bh = *(const s8v*)(g_whi + bbase);
      s8v bl = *(const s8v*)(g_wlo + bbase);
#pragma unroll
      for (int a = 0; a < 4; ++a) {
        acc[a][s] = __builtin_amdgcn_mfma_f32_16x16x32_bf16(ah[a], bh, acc[a][s], 0, 0, 0);
        acc[a][s] = __builtin_amdgcn_mfma_f32_16x16x32_bf16(ah[a], bl, acc[a][s], 0, 0, 0);
        acc[a][s] = __builtin_amdgcn_mfma_f32_16x16x32_bf16(al[a], bh, acc[a][s], 0, 0, 0);
      }
    }
  }
  __shared__ float red[4][64];
  const int isb = g_flag;
#pragma unroll
  for (int s = 0; s < 4; ++s) {
    float m4 = -FMAX;
#pragma unroll
    for (int a = 0; a < 4; ++a)
#pragma unroll
      for (int r = 0; r < 4; ++r) m4 = fmaxf(m4, acc[a][s][r]);
#pragma unroll
    for (int off = 16; off < 64; off <<= 1) m4 = fmaxf(m4, __shfl_down(m4, off, 64));
    if (quad == 0) red[wave][s * 16 + l16] = m4;
  }
  __syncthreads();
  if (tid < 64) {
    float m = fmaxf(fmaxf(red[0][tid], red[1][tid]), fmaxf(red[2][tid], red[3][tid]));
    int o = o0 + tid;
    float sv = ldany(s5, o, isb), tv = ldany(t5, o, isb);
    float h = sv * m + tv;
    h = (h >= 0.f) ? h : NEG * h;
    g_ws_f[OFF_PART + ((size_t)b * 1024 + o) * 8 + blockIdx.x] = h;
  }
}

__global__ void poolred_kernel() {
  const float* part = g_ws_f + OFF_PART;
  float* pooled = g_ws_f + OFF_POOLED;
  int i = blockIdx.x * blockDim.x + threadIdx.x;
  if (i >= 8 * 1024) return;
  const float* p = part + (size_t)i * 8;
  float m = -FMAX;
#pragma unroll
  for (int j = 0; j < 8; ++j) m = fmaxf(m, p[j]);
  pooled[i] = m;
}

// ---------------- FC: one wave per output ----------------
__global__ void fc_kernel(size_t inoff, const void* W, const void* bias,
                          const void* s, const void* t, size_t outoff, int has_out,
                          void* OUTB, int Bb, int IC, int OC, int act) {
  const int isb = g_flag;
  const float* IN = g_ws_f + inoff;
  int gw = (blockIdx.x * blockDim.x + threadIdx.x) >> 6;
  int lane = threadIdx.x & 63;
  if (gw >= Bb * OC) return;
  int b = gw / OC, o = gw % OC;
  const float* in = IN + (size_t)b * IC;
  float acc = 0.f;
  for (int c = lane; c < IC; c += 64) acc += in[c] * ldany(W, (size_t)o * IC + c, isb);
#pragma unroll
  for (int off = 32; off > 0; off >>= 1) acc += __shfl_down(acc, off, 64);
  if (lane == 0) {
    float h = acc;
    if (bias) h += ldany(bias, o, isb);
    if (s) h = h * ldany(s, o, isb) + ldany(t, o, isb);
    if (act) h = (h >= 0.f) ? h : NEG * h;
    if (has_out) g_ws_f[outoff + (size_t)b * OC + o] = h;
    if (OUTB) {
      if (isb) ((bf16*)OUTB)[(size_t)b * OC + o] = __float2bfloat16(h);
      else ((float*)OUTB)[(size_t)b * OC + o] = h;
    }
  }
}

extern "C" void kernel_launch(void* const* d_in, const int* in_sizes, int n_in,
                              void* d_out, int out_size, void* d_ws, size_t ws_size,
                              hipStream_t stream) {
  const int B = 8, N = 2048, BN = B * N;
  const void* points = d_in[0];
  const void *W1 = d_in[1], *s1 = d_in[2], *t1 = d_in[3];
  const void *W2 = d_in[4], *s2 = d_in[5], *t2 = d_in[6];
  const void *W3 = d_in[7], *s3 = d_in[8], *t3 = d_in[9];
  const void *W4 = d_in[10], *s4 = d_in[11], *t4 = d_in[12];
  const void *W5 = d_in[13], *s5 = d_in[14], *t5 = d_in[15];
  const void *Wf1 = d_in[16], *sf1 = d_in[17], *tf1 = d_in[18];
  const void *Wf2 = d_in[19], *bf2 = d_in[20], *sf2 = d_in[21], *tf2 = d_in[22];
  const void *Wf3 = d_in[23], *bf3 = d_in[24];

  probe_kernel<<<1, 1, 0, stream>>>(points);
  split_kernel<<<(1024 * 512) / 256, 256, 0, stream>>>(W5, 512, 512, 4, 1, 1024 * 512);
  split_w<<<dim3(2048 / 256, 2), 256, 0, stream>>>(W1, 3, 0, WB1, 2048, 2048);
  split_w<<<dim3(4096 / 256, 2), 256, 0, stream>>>(W2, 64, 1, WB2, 4096, 4096);
  split_w<<<dim3(8192 / 256, 2), 256, 0, stream>>>(W3, 64, 1, WB3, 8192, 8192);
  split_w<<<dim3(32768 / 256, 2), 256, 0, stream>>>(W4, 128, 2, WB4, 32768, 32768);

  // ---- layer 1: points (C=3, CPAD=32) -> cols 0:64
  norms_kernel<<<BN / 4, 256, 0, stream>>>(points, 3, 3, BN);
  split_kernel<<<(BN * 32) / 256, 256, 0, stream>>>(points, 3, 3, 0, 0, BN * 32);
  knn_fused<32><<<dim3(N / 64, B, NPART), 256, 0, stream>>>(N);
  gmat_mfma<32><<<dim3(BN / 64, 1, 2), 256, 0, stream>>>(WB1, 2048, BN);
  edge_epi64<<<dim3(BN / 4, 1), 256, 0, stream>>>(s1, t1, 0, 1, 1, BN, N);
  // ---- layer 2: (C=64, CPAD=64) -> cols 64:128
  knn_fused<64><<<dim3(N / 64, B, NPART), 256, 0, stream>>>(N);
  gmat_mfma<64><<<dim3(BN / 64, 1, 2), 256, 0, stream>>>(WB2, 4096, BN);
  edge_epi64<<<dim3(BN / 4, 1), 256, 0, stream>>>(s2, t2, 64, 1, 1, BN, N);
  // ---- layer 3: (C=64) -> cols 128:256, 2 chunks; next layer CPAD=128
  knn_fused<64><<<dim3(N / 64, B, NPART), 256, 0, stream>>>(N);
  gmat_mfma<64><<<dim3(BN / 64, 2, 2), 256, 0, stream>>>(WB3, 8192, BN);
  zero_norms<<<BN / 256, 256, 0, stream>>>();
  edge_epi64<<<dim3(BN / 4, 2), 256, 0, stream>>>(s3, t3, 128, 2, 2, BN, N);
  // ---- layer 4: (C=128) -> cols 256:512, 4 chunks; no next knn
  knn_fused<128><<<dim3(N / 64, B, NPART), 256, 0, stream>>>(N);
  gmat_mfma<128><<<dim3(BN / 64, 4, 2), 256, 0, stream>>>(WB4, 32768, BN);
  edge_epi64<<<dim3(BN / 4, 4), 256, 0, stream>>>(s4, t4, 256, -1, 0, BN, N);
  // ---- W5 + global max pool
  w5max_mfma<<<dim3(8, 16, 8), 256, 0, stream>>>(s5, t5, N);
  poolred_kernel<<<32, 256, 0, stream>>>();
  // ---- FC head
  fc_kernel<<<(8 * 512 * 64) / 256, 256, 0, stream>>>(OFF_POOLED, Wf1, nullptr, sf1, tf1, OFF_H1, 1, nullptr, 8, 1024, 512, 1);
  fc_kernel<<<(8 * 256 * 64) / 256, 256, 0, stream>>>(OFF_H1, Wf2, bf2, sf2, tf2, OFF_H2, 1, nullptr, 8, 512, 256, 1);
  fc_kernel<<<6, 256, 0, stream>>>(OFF_H2, Wf3, bf3, nullptr, nullptr, 0, 0, d_out, 8, 256, 3, 0);
}